// Round 7
// baseline (340.875 us; speedup 1.0000x reference)
//
#include <hip/hip_runtime.h>
#include <math.h>

#define NN 50000
#define NPAD 50048      // 782 * 64
#define NTILES 3128     // NPAD / 16
#define NE 600000
#define H 128
#define ET 8
#define EPS 1e-5f
#define INVSQ 0.08838834764831845f  // 1/sqrt(128)

typedef __attribute__((ext_vector_type(8))) short bf16x8;
typedef __attribute__((ext_vector_type(8))) unsigned short u16x8;
typedef __attribute__((ext_vector_type(4))) float f32x4;

static __device__ inline float bf_lo(unsigned int w) { return __uint_as_float(w << 16); }
static __device__ inline float bf_hi(unsigned int w) { return __uint_as_float(w & 0xFFFF0000u); }
static __device__ inline float bfu(unsigned short v) {
  return __uint_as_float((unsigned int)v << 16);
}
static __device__ inline unsigned short f2bf(float f) {
  unsigned int u = __float_as_uint(f);
  return (unsigned short)((u + 0x7FFFu + ((u >> 16) & 1u)) >> 16);  // RNE
}

// ================= fused prep: hidden->bf16, weights->bf16^T, etype tables, degree hist =======
#define PH_B 3125
#define PW_B 384
#define ET_B 8
#define HIST_B 2344

__global__ __launch_bounds__(256) void prep_all_kernel(
    const float* __restrict__ hidden, const float* __restrict__ edge_emb,
    const float* __restrict__ Wq, const float* __restrict__ Wk, const float* __restrict__ Wv,
    const float* __restrict__ W1, const float* __restrict__ W2,
    const float* __restrict__ Web, const float* __restrict__ beb,
    const int* __restrict__ tgt,
    unsigned short* __restrict__ hcat, unsigned short* __restrict__ WqkvT,
    unsigned short* __restrict__ W1T, unsigned short* __restrict__ W2T,
    float* __restrict__ Kef, float* __restrict__ Vef, float* __restrict__ ebuf,
    int* __restrict__ deg) {
  const int blk = blockIdx.x;
  const int t = threadIdx.x;
  if (blk < PH_B) {
    // hidden fp32 -> bf16 into hcat[:, 0:128] (row stride 256)
    int g = blk * 256 + t;  // NN*16 = 800000 exactly
    int row = g >> 4, seg = g & 15;
    const float4* src = (const float4*)(hidden + (size_t)row * 128 + seg * 8);
    float4 x0 = src[0], x1 = src[1];
    u16x8 o;
    o[0] = f2bf(x0.x); o[1] = f2bf(x0.y); o[2] = f2bf(x0.z); o[3] = f2bf(x0.w);
    o[4] = f2bf(x1.x); o[5] = f2bf(x1.y); o[6] = f2bf(x1.z); o[7] = f2bf(x1.w);
    *(u16x8*)(hcat + (size_t)row * 256 + seg * 8) = o;
  } else if (blk < PH_B + PW_B) {
    int idx = (blk - PH_B) * 256 + t;
    if (idx < 49152) {
      int r = idx >> 7, k = idx & 127;
      const float* W = (r < 128) ? Wq : (r < 256) ? Wk : Wv;
      WqkvT[idx] = f2bf(W[k * 128 + (r & 127)]);
    } else if (idx < 81920) {
      int j = idx - 49152;
      int r = j >> 8, k = j & 255;
      W1T[j] = f2bf(W1[k * 128 + r]);
    } else if (idx < 98304) {
      int j = idx - 81920;
      int r = j >> 7, k = j & 127;
      W2T[j] = f2bf(W2[k * 128 + r]);
    }
  } else if (blk < PH_B + PW_B + ET_B) {
    // per-edge-type tables (fp32): Kef = ee@Wk, Vef = ee@Wv, eb = ee@Web + beb
    int e = blk - (PH_B + PW_B);
    if (t < 128) {
      float sk = 0.f, sv = 0.f;
      for (int i = 0; i < 128; ++i) {
        float ev = edge_emb[e * 128 + i];
        sk = fmaf(ev, Wk[i * 128 + t], sk);
        sv = fmaf(ev, Wv[i * 128 + t], sv);
      }
      Kef[e * 128 + t] = sk;
      Vef[e * 128 + t] = sv;
    } else if (t == 128) {
      float s2 = beb[0];
      for (int i = 0; i < 128; ++i) s2 = fmaf(edge_emb[e * 128 + i], Web[i], s2);
      ebuf[e] = s2;
    }
  } else {
    int e = (blk - (PH_B + PW_B + ET_B)) * 256 + t;
    if (e < NE) atomicAdd(&deg[tgt[e]], 1);
  }
}

// ---------------- QKV GEMM via MFMA + fused qke table ----------------
// 8 waves: 2 row-groups x 4 col-groups. After staging, thread t also computes
// qke[node = blk*64 + (t>>3)][et = t&7] = Q_scaled . Kef[et] + eb[et].
__global__ __launch_bounds__(512) void qkv_mfma_kernel(
    const unsigned short* __restrict__ hcat, const unsigned short* __restrict__ WqkvT,
    const float* __restrict__ bq, const float* __restrict__ bk, const float* __restrict__ bv,
    const float* __restrict__ Kef, const float* __restrict__ ebuf,
    unsigned short* __restrict__ Qb, unsigned short* __restrict__ KV_u16,
    float* __restrict__ qke) {
  __shared__ unsigned short stage[64][392];
  const int tid = threadIdx.x;
  const int w = tid >> 6, l = tid & 63;
  const int wr = w >> 2, wc = w & 3;
  const int lr = l & 15, lg = l >> 4;
  const int blk = blockIdx.x;

  f32x4 acc[2][6] = {};
  const unsigned short* Ab = hcat + (size_t)(blk * 64 + wr * 32 + lr) * 256 + lg * 8;
  const unsigned short* Bb = WqkvT + (size_t)(wc * 96 + lr) * 128 + lg * 8;
#pragma unroll
  for (int ks = 0; ks < 4; ++ks) {
    bf16x8 a0 = *(const bf16x8*)(Ab + ks * 32);
    bf16x8 a1 = *(const bf16x8*)(Ab + 16 * 256 + ks * 32);
#pragma unroll
    for (int ct = 0; ct < 6; ++ct) {
      bf16x8 b = *(const bf16x8*)(Bb + ct * 16 * 128 + ks * 32);
      acc[0][ct] = __builtin_amdgcn_mfma_f32_16x16x32_bf16(a0, b, acc[0][ct], 0, 0, 0);
      acc[1][ct] = __builtin_amdgcn_mfma_f32_16x16x32_bf16(a1, b, acc[1][ct], 0, 0, 0);
    }
  }
  // bias + scale + convert -> LDS stage in FINAL memory layout:
  //   row u16 layout: [0,128)   = Q col c (scaled by 1/sqrt(128))
  //                   [128,384) = KV interleave: K col j -> 128 + (j>>1)*4 + (j&1)
  //                               V col j -> 128 + (j>>1)*4 + 2 + (j&1)
#pragma unroll
  for (int ct = 0; ct < 6; ++ct) {
    int c = wc * 96 + ct * 16 + lr;
    float bias = (c < 128) ? bq[c] : (c < 256) ? bk[c - 128] : bv[c - 256];
    float sc = (c < 128) ? INVSQ : 1.f;
    int off;
    if (c < 128) off = c;
    else if (c < 256) { int j = c - 128; off = 128 + ((j >> 1) << 2) + (j & 1); }
    else { int j = c - 256; off = 128 + ((j >> 1) << 2) + 2 + (j & 1); }
#pragma unroll
    for (int mt = 0; mt < 2; ++mt)
#pragma unroll
      for (int j = 0; j < 4; ++j)
        stage[wr * 32 + mt * 16 + lg * 4 + j][off] = f2bf((acc[mt][ct][j] + bias) * sc);
  }
  __syncthreads();
  // coalesced 16B stores
  for (int idx = tid; idx < 64 * 48; idx += 512) {
    int r = idx / 48, g = idx % 48;
    int row = blk * 64 + r;
    if (row >= NN) continue;
    u16x8 v = *(const u16x8*)(&stage[r][g * 8]);
    if (g < 16) *(u16x8*)(Qb + (size_t)row * 128 + g * 8) = v;
    else *(u16x8*)(KV_u16 + (size_t)row * 256 + (g - 16) * 8) = v;
  }
  // fused qke: thread t -> (row = t>>3, et = t&7); Q (scaled) read from stage.
  {
    int row = tid >> 3, et = tid & 7;
    int node = blk * 64 + row;
    if (node < NN) {
      const float* kf = Kef + et * 128;
      const unsigned short* qs = &stage[row][0];
      float d = 0.f;
#pragma unroll 16
      for (int c = 0; c < 128; c += 2) {
        unsigned int w2 = *(const unsigned int*)(qs + c);
        d = fmaf(bf_lo(w2), kf[c], d);
        d = fmaf(bf_hi(w2), kf[c + 1], d);
      }
      qke[(size_t)node * 8 + et] = d + ebuf[et];
    }
  }
}

// ---------------- CSR build: scans + scatter ----------------
__global__ __launch_bounds__(256) void scan1_kernel(const int* __restrict__ deg,
                                                    int* __restrict__ excl,
                                                    int* __restrict__ sums) {
  __shared__ int buf[256];
  int idx = blockIdx.x * 256 + threadIdx.x;
  int v = (idx < NN) ? deg[idx] : 0;
  buf[threadIdx.x] = v;
  __syncthreads();
  for (int o = 1; o < 256; o <<= 1) {
    int tv = (threadIdx.x >= o) ? buf[threadIdx.x - o] : 0;
    __syncthreads();
    buf[threadIdx.x] += tv;
    __syncthreads();
  }
  if (idx < NN) excl[idx] = buf[threadIdx.x] - v;
  if (threadIdx.x == 255) sums[blockIdx.x] = buf[255];
}

__global__ __launch_bounds__(256) void scan2_kernel(int* __restrict__ sums, int nb) {
  __shared__ int buf[256];
  int v = (threadIdx.x < nb) ? sums[threadIdx.x] : 0;
  buf[threadIdx.x] = v;
  __syncthreads();
  for (int o = 1; o < 256; o <<= 1) {
    int tv = (threadIdx.x >= o) ? buf[threadIdx.x - o] : 0;
    __syncthreads();
    buf[threadIdx.x] += tv;
    __syncthreads();
  }
  if (threadIdx.x < nb) sums[threadIdx.x] = buf[threadIdx.x] - v;  // exclusive
}

__global__ __launch_bounds__(256) void scan3_kernel(const int* __restrict__ excl,
                                                    const int* __restrict__ sums,
                                                    int* __restrict__ row_off,
                                                    int* __restrict__ cursor) {
  int idx = blockIdx.x * 256 + threadIdx.x;
  if (idx < NN) {
    int r = excl[idx] + sums[blockIdx.x];
    row_off[idx] = r;
    cursor[idx] = r;
  }
  if (idx == 0) row_off[NN] = NE;
}

__global__ void scatter_kernel(const int* __restrict__ src, const int* __restrict__ tgt,
                               const int* __restrict__ et, int* __restrict__ cursor,
                               int* __restrict__ packed) {
  int e = blockIdx.x * blockDim.x + threadIdx.x;
  if (e < NE) {
    int pos = atomicAdd(&cursor[tgt[e]], 1);
    packed[pos] = src[e] | (et[e] << 16);  // src < 65536, et < 8
  }
}

// ---------------- attention: one wave/node, 16 lanes/edge, 8 edges in flight --------------
// No-max softmax (logit range ~±8 is safe in fp32). qke folds q·Ke + eb per (node, etype).
__global__ __launch_bounds__(256) void attn_kernel(
    const unsigned short* __restrict__ Qb, const uint4* __restrict__ KV4,
    const float* __restrict__ qke, const float* __restrict__ Vef,
    const int* __restrict__ row_off, const int* __restrict__ packed,
    unsigned short* __restrict__ hcat_u16) {
  const int wid = (blockIdx.x * blockDim.x + threadIdx.x) >> 6;
  const int lane = threadIdx.x & 63;
  const int g = lane >> 4, m = lane & 15;
  const int beg = row_off[wid], end = row_off[wid + 1];
  // q: 8 cols starting 8m (bf16, pre-scaled by 1/sqrt(128))
  u16x8 qv = *(const u16x8*)(Qb + (size_t)wid * 128 + m * 8);
  float q[8];
#pragma unroll
  for (int j = 0; j < 8; ++j) q[j] = bfu(qv[j]);
  const float* qkb = qke + (size_t)wid * 8;
  float a[8] = {0.f, 0.f, 0.f, 0.f, 0.f, 0.f, 0.f, 0.f};
  float s = 0.f;
  for (int i = beg; i < end; i += 8) {
    int iA = i + g, iB = i + 4 + g;
    bool vA = iA < end, vB = iB < end;
    int pA = packed[vA ? iA : beg];
    int pB = packed[vB ? iB : beg];
    int sA = pA & 0xFFFF, eA = pA >> 16;
    int sB = pB & 0xFFFF, eB = pB >> 16;
    // KV row = 32 uint4; lane m reads uint4 2m, 2m+1 (cols 8m..8m+7)
    const uint4* rowA = KV4 + (size_t)sA * 32 + m * 2;
    const uint4* rowB = KV4 + (size_t)sB * 32 + m * 2;
    uint4 xA0 = rowA[0], xA1 = rowA[1];
    uint4 xB0 = rowB[0], xB1 = rowB[1];
    // x: {kpair, vpair, kpair, vpair}
    float dA, dB;
    dA = bf_lo(xA0.x) * q[0];
    dB = bf_lo(xB0.x) * q[0];
    dA = fmaf(bf_hi(xA0.x), q[1], dA);
    dB = fmaf(bf_hi(xB0.x), q[1], dB);
    dA = fmaf(bf_lo(xA0.z), q[2], dA);
    dB = fmaf(bf_lo(xB0.z), q[2], dB);
    dA = fmaf(bf_hi(xA0.z), q[3], dA);
    dB = fmaf(bf_hi(xB0.z), q[3], dB);
    dA = fmaf(bf_lo(xA1.x), q[4], dA);
    dB = fmaf(bf_lo(xB1.x), q[4], dB);
    dA = fmaf(bf_hi(xA1.x), q[5], dA);
    dB = fmaf(bf_hi(xB1.x), q[5], dB);
    dA = fmaf(bf_lo(xA1.z), q[6], dA);
    dB = fmaf(bf_lo(xB1.z), q[6], dB);
    dA = fmaf(bf_hi(xA1.z), q[7], dA);
    dB = fmaf(bf_hi(xB1.z), q[7], dB);
#pragma unroll
    for (int o = 8; o >= 1; o >>= 1) {
      dA += __shfl_xor(dA, o);
      dB += __shfl_xor(dB, o);
    }
    float peA = __expf(dA + qkb[eA]);
    float peB = __expf(dB + qkb[eB]);
    peA = vA ? peA : 0.f;
    peB = vB ? peB : 0.f;
    s += peA + peB;
    const float4* vefA = (const float4*)(Vef + eA * 128 + m * 8);
    const float4* vefB = (const float4*)(Vef + eB * 128 + m * 8);
    float4 vA0 = vefA[0], vA1 = vefA[1];
    float4 vB0 = vefB[0], vB1 = vefB[1];
    a[0] = fmaf(peA, bf_lo(xA0.y) + vA0.x, a[0]);
    a[1] = fmaf(peA, bf_hi(xA0.y) + vA0.y, a[1]);
    a[2] = fmaf(peA, bf_lo(xA0.w) + vA0.z, a[2]);
    a[3] = fmaf(peA, bf_hi(xA0.w) + vA0.w, a[3]);
    a[4] = fmaf(peA, bf_lo(xA1.y) + vA1.x, a[4]);
    a[5] = fmaf(peA, bf_hi(xA1.y) + vA1.y, a[5]);
    a[6] = fmaf(peA, bf_lo(xA1.w) + vA1.z, a[6]);
    a[7] = fmaf(peA, bf_hi(xA1.w) + vA1.w, a[7]);
    a[0] = fmaf(peB, bf_lo(xB0.y) + vB0.x, a[0]);
    a[1] = fmaf(peB, bf_hi(xB0.y) + vB0.y, a[1]);
    a[2] = fmaf(peB, bf_lo(xB0.w) + vB0.z, a[2]);
    a[3] = fmaf(peB, bf_hi(xB0.w) + vB0.w, a[3]);
    a[4] = fmaf(peB, bf_lo(xB1.y) + vB1.x, a[4]);
    a[5] = fmaf(peB, bf_hi(xB1.y) + vB1.y, a[5]);
    a[6] = fmaf(peB, bf_lo(xB1.w) + vB1.z, a[6]);
    a[7] = fmaf(peB, bf_hi(xB1.w) + vB1.w, a[7]);
  }
  // cross-group reduce (xor 16, 32)
#pragma unroll
  for (int o = 16; o <= 32; o <<= 1) {
    s += __shfl_xor(s, o);
#pragma unroll
    for (int j = 0; j < 8; ++j) a[j] += __shfl_xor(a[j], o);
  }
  if (g == 0) {
    float inv = (s > 0.f) ? 1.f / s : 0.f;
    u16x8 o;
#pragma unroll
    for (int j = 0; j < 8; ++j) o[j] = f2bf(a[j] * inv);
    *(u16x8*)(hcat_u16 + (size_t)wid * 256 + 128 + m * 8) = o;
  }
}

// ---------------- FFN + residual + LayerNorm (MFMA, weights in LDS, persistent waves) -------
// 256 blocks x 768 threads (12 waves = 3/SIMD). W1T (64KB) + W2T (32KB) staged once into LDS
// with XOR swizzle (^((row&7)<<4)); per-wave mid buffers (51KB). Total LDS 147KB.
__global__ __launch_bounds__(768) void ffn_mfma_kernel(
    const unsigned short* __restrict__ hcat, const float* __restrict__ hidden,
    const unsigned short* __restrict__ W1T, const unsigned short* __restrict__ W2T,
    const float* __restrict__ b1, const float* __restrict__ b2,
    const float* __restrict__ gamma, const float* __restrict__ beta,
    float* __restrict__ out) {
  __shared__ unsigned short w1s[32768];       // 64KB swizzled [128][256]
  __shared__ unsigned short w2s[16384];       // 32KB swizzled [128][128]
  __shared__ unsigned short mids[12][2176];   // per-wave 16 x 136
  const int tid = threadIdx.x;
  const int w = tid >> 6, l = tid & 63;
  const int lr = l & 15, lg = l >> 4;

  // ---- stage weights (once per block) ----
#pragma unroll
  for (int it = 0; it < 6; ++it) {
    int idx = it * 768 + tid;                // 4096 segs of 8 u16
    if (idx < 4096) {
      int c = idx >> 5, ks8 = idx & 31;
      u16x8 v = *(const u16x8*)(W1T + c * 256 + ks8 * 8);
      int byte = (c * 512 + ks8 * 16) ^ ((c & 7) << 4);
      *(u16x8*)((char*)w1s + byte) = v;
    }
  }
#pragma unroll
  for (int it = 0; it < 3; ++it) {
    int idx = it * 768 + tid;                // 2048 segs
    if (idx < 2048) {
      int c = idx >> 4, ks8 = idx & 15;
      u16x8 v = *(const u16x8*)(W2T + c * 128 + ks8 * 8);
      int byte = (c * 256 + ks8 * 16) ^ ((c & 7) << 4);
      *(u16x8*)((char*)w2s + byte) = v;
    }
  }
  __syncthreads();

  // ---- per-lane constants ----
  float bias1[8], bias2[8], ga[8], be[8];
#pragma unroll
  for (int ct = 0; ct < 8; ++ct) {
    int c = ct * 16 + lr;
    bias1[ct] = b1[c];
    bias2[ct] = b2[c];
    ga[ct] = gamma[c];
    be[ct] = beta[c];
  }
  unsigned short* midw = mids[w];
  const char* w1b = (const char*)w1s;
  const char* w2b = (const char*)w2s;

  for (int t = blockIdx.x * 12 + w; t < NTILES; t += 3072) {
    // A fragments (K=256): 8 x 16B from hcat
    const unsigned short* Ab = hcat + (size_t)(t * 16 + lr) * 256 + lg * 8;
    bf16x8 a[8];
#pragma unroll
    for (int ks = 0; ks < 8; ++ks) a[ks] = *(const bf16x8*)(Ab + ks * 32);

    // GEMM1: K=256 -> 128, B from LDS
    f32x4 acc[8] = {};
#pragma unroll
    for (int ks = 0; ks < 8; ++ks) {
#pragma unroll
      for (int ct = 0; ct < 8; ++ct) {
        int byte = ((ct * 16 + lr) * 512 + (lg * 8 + ks * 32) * 2) ^ ((lr & 7) << 4);
        bf16x8 b = *(const bf16x8*)(w1b + byte);
        acc[ct] = __builtin_amdgcn_mfma_f32_16x16x32_bf16(a[ks], b, acc[ct], 0, 0, 0);
      }
    }

    // residual prefetch (consumed in epilogue; latency hidden under GEMM2)
    float res[8][4];
#pragma unroll
    for (int ct = 0; ct < 8; ++ct)
#pragma unroll
      for (int j = 0; j < 4; ++j) {
        int r = t * 16 + lg * 4 + j;
        res[ct][j] = (r < NN) ? hidden[(size_t)r * 128 + ct * 16 + lr] : 0.f;
      }

    // silu -> per-wave mid buffer
#pragma unroll
    for (int ct = 0; ct < 8; ++ct) {
      float bb = bias1[ct];
#pragma unroll
      for (int j = 0; j < 4; ++j) {
        float x = acc[ct][j] + bb;
        float sl = x / (1.f + __expf(-x));
        midw[(lg * 4 + j) * 136 + ct * 16 + lr] = f2bf(sl);
      }
    }
    asm volatile("s_waitcnt lgkmcnt(0)" ::: "memory");
    __builtin_amdgcn_sched_barrier(0);

    // GEMM2: K=128 -> 128, A from mid, B from LDS
    f32x4 acc2[8] = {};
#pragma unroll
    for (int ks = 0; ks < 4; ++ks) {
      bf16x8 a2 = *(const bf16x8*)(midw + lr * 136 + lg * 8 + ks * 32);
#pragma unroll
      for (int ct = 0; ct < 8; ++ct) {
        int byte = ((ct * 16 + lr) * 256 + (lg * 8 + ks * 32) * 2) ^ ((lr & 7) << 4);
        bf16x8 b = *(const bf16x8*)(w2b + byte);
        acc2[ct] = __builtin_amdgcn_mfma_f32_16x16x32_bf16(a2, b, acc2[ct], 0, 0, 0);
      }
    }

    // epilogue: + b2 + residual, LayerNorm, store
    float x[8][4];
#pragma unroll
    for (int ct = 0; ct < 8; ++ct)
#pragma unroll
      for (int j = 0; j < 4; ++j) x[ct][j] = acc2[ct][j] + bias2[ct] + res[ct][j];
#pragma unroll
    for (int j = 0; j < 4; ++j) {
      float s = 0.f, ss = 0.f;
#pragma unroll
      for (int ct = 0; ct < 8; ++ct) {
        s += x[ct][j];
        ss += x[ct][j] * x[ct][j];
      }
#pragma unroll
      for (int o = 8; o >= 1; o >>= 1) {
        s += __shfl_xor(s, o);
        ss += __shfl_xor(ss, o);
      }
      float mu = s * (1.f / 128.f);
      float inv = rsqrtf(ss * (1.f / 128.f) - mu * mu + EPS);
      int r = t * 16 + lg * 4 + j;
      if (r < NN) {
#pragma unroll
        for (int ct = 0; ct < 8; ++ct) {
          int c = ct * 16 + lr;
          out[(size_t)r * 128 + c] = (x[ct][j] - mu) * inv * ga[ct] + be[ct];
        }
      }
    }
  }
}

extern "C" void kernel_launch(void* const* d_in, const int* in_sizes, int n_in,
                              void* d_out, int out_size, void* d_ws, size_t ws_size,
                              hipStream_t stream) {
  const float* hidden = (const float*)d_in[0];
  const int* edge_index = (const int*)d_in[1];
  const int* edge_type = (const int*)d_in[2];
  const float* edge_emb = (const float*)d_in[3];
  const float* Wq = (const float*)d_in[4];
  const float* bq = (const float*)d_in[5];
  const float* Wk = (const float*)d_in[6];
  const float* bk = (const float*)d_in[7];
  const float* Wv = (const float*)d_in[8];
  const float* bv = (const float*)d_in[9];
  const float* Web = (const float*)d_in[10];
  const float* beb = (const float*)d_in[11];
  const float* W1 = (const float*)d_in[12];
  const float* b1 = (const float*)d_in[13];
  const float* W2 = (const float*)d_in[14];
  const float* b2 = (const float*)d_in[15];
  const float* gamma = (const float*)d_in[16];
  const float* beta = (const float*)d_in[17];
  float* out = (float*)d_out;

  const int* srcp = edge_index;
  const int* tgtp = edge_index + NE;

  size_t off = 0;
  auto alloc = [&](size_t bytes) {
    void* p = (char*)d_ws + off;
    off += (bytes + 255) & ~(size_t)255;
    return p;
  };
  unsigned short* hcat = (unsigned short*)alloc((size_t)NPAD * 256 * 2);  // [h|agg] bf16
  unsigned short* Qb = (unsigned short*)alloc((size_t)NPAD * 128 * 2);    // pre-scaled
  unsigned short* KV = (unsigned short*)alloc((size_t)NPAD * 256 * 2);    // interleaved k/v pairs
  unsigned short* WqkvT = (unsigned short*)alloc(384 * 128 * 2);
  unsigned short* W1T = (unsigned short*)alloc(128 * 256 * 2);
  unsigned short* W2T = (unsigned short*)alloc(128 * 128 * 2);
  float* Kef = (float*)alloc(ET * H * 4);
  float* Vef = (float*)alloc(ET * H * 4);
  float* ebuf = (float*)alloc(ET * 4);
  float* qke = (float*)alloc((size_t)NN * 8 * 4);
  int* deg = (int*)alloc((size_t)NN * 4);
  int* excl = (int*)alloc((size_t)NN * 4);
  int* sums = (int*)alloc(256 * 4);
  int* row_off = (int*)alloc((size_t)(NN + 1) * 4);
  int* cursor = (int*)alloc((size_t)NN * 4);
  int* packed = (int*)alloc((size_t)NE * 4);

  hipMemsetAsync(deg, 0, (size_t)NN * 4, stream);

  const int scan_blocks = (NN + 255) / 256;  // 196

  prep_all_kernel<<<PH_B + PW_B + ET_B + HIST_B, 256, 0, stream>>>(
      hidden, edge_emb, Wq, Wk, Wv, W1, W2, Web, beb, tgtp, hcat, WqkvT, W1T, W2T, Kef, Vef,
      ebuf, deg);
  scan1_kernel<<<scan_blocks, 256, 0, stream>>>(deg, excl, sums);
  scan2_kernel<<<1, 256, 0, stream>>>(sums, scan_blocks);
  scan3_kernel<<<scan_blocks, 256, 0, stream>>>(excl, sums, row_off, cursor);
  scatter_kernel<<<(NE + 255) / 256, 256, 0, stream>>>(srcp, tgtp, edge_type, cursor, packed);
  qkv_mfma_kernel<<<NPAD / 64, 512, 0, stream>>>(hcat, WqkvT, bq, bk, bv, Kef, ebuf, Qb, KV,
                                                 qke);
  attn_kernel<<<(NN * 64) / 256, 256, 0, stream>>>(Qb, (const uint4*)KV, qke, Vef, row_off,
                                                   packed, hcat);
  ffn_mfma_kernel<<<256, 768, 0, stream>>>(hcat, hidden, W1T, W2T, b1, b2, gamma, beta, out);
}

// Round 10
// 324.378 us; speedup vs baseline: 1.0509x; 1.0509x over previous
//
#include <hip/hip_runtime.h>
#include <math.h>

#define NN 50000
#define NPAD 50048      // 782 * 64
#define NTILES 3128     // NPAD / 16
#define NE 600000
#define H 128
#define ET 8
#define EPS 1e-5f
#define INVSQ 0.08838834764831845f  // 1/sqrt(128)

typedef __attribute__((ext_vector_type(8))) short bf16x8;
typedef __attribute__((ext_vector_type(8))) unsigned short u16x8;
typedef __attribute__((ext_vector_type(4))) float f32x4;

static __device__ inline float bf_lo(unsigned int w) { return __uint_as_float(w << 16); }
static __device__ inline float bf_hi(unsigned int w) { return __uint_as_float(w & 0xFFFF0000u); }
static __device__ inline float bfu(unsigned short v) {
  return __uint_as_float((unsigned int)v << 16);
}
static __device__ inline unsigned short f2bf(float f) {
  unsigned int u = __float_as_uint(f);
  return (unsigned short)((u + 0x7FFFu + ((u >> 16) & 1u)) >> 16);  // RNE
}

// ================= fused prep: hidden->bf16, weights->bf16^T, etype tables, degree hist =======
#define PH_B 3125
#define PW_B 384
#define ET_B 8
#define HIST_B 2344

__global__ __launch_bounds__(256) void prep_all_kernel(
    const float* __restrict__ hidden, const float* __restrict__ edge_emb,
    const float* __restrict__ Wq, const float* __restrict__ Wk, const float* __restrict__ Wv,
    const float* __restrict__ W1, const float* __restrict__ W2,
    const float* __restrict__ Web, const float* __restrict__ beb,
    const int* __restrict__ tgt,
    unsigned short* __restrict__ hcat, unsigned short* __restrict__ WqkvT,
    unsigned short* __restrict__ W1T, unsigned short* __restrict__ W2T,
    unsigned short* __restrict__ KefTT, float* __restrict__ Vef, float* __restrict__ ebuf,
    int* __restrict__ deg) {
  const int blk = blockIdx.x;
  const int t = threadIdx.x;
  if (blk < PH_B) {
    // hidden fp32 -> bf16 into hcat[:, 0:128] (row stride 256)
    int g = blk * 256 + t;  // NN*16 = 800000 exactly
    int row = g >> 4, seg = g & 15;
    const float4* src = (const float4*)(hidden + (size_t)row * 128 + seg * 8);
    float4 x0 = src[0], x1 = src[1];
    u16x8 o;
    o[0] = f2bf(x0.x); o[1] = f2bf(x0.y); o[2] = f2bf(x0.z); o[3] = f2bf(x0.w);
    o[4] = f2bf(x1.x); o[5] = f2bf(x1.y); o[6] = f2bf(x1.z); o[7] = f2bf(x1.w);
    *(u16x8*)(hcat + (size_t)row * 256 + seg * 8) = o;
  } else if (blk < PH_B + PW_B) {
    int idx = (blk - PH_B) * 256 + t;
    if (idx < 49152) {
      int r = idx >> 7, k = idx & 127;
      const float* W = (r < 128) ? Wq : (r < 256) ? Wk : Wv;
      WqkvT[idx] = f2bf(W[k * 128 + (r & 127)]);
    } else if (idx < 81920) {
      int j = idx - 49152;
      int r = j >> 8, k = j & 255;
      W1T[j] = f2bf(W1[k * 128 + r]);
    } else if (idx < 98304) {
      int j = idx - 81920;
      int r = j >> 7, k = j & 127;
      W2T[j] = f2bf(W2[k * 128 + r]);
    }
  } else if (blk < PH_B + PW_B + ET_B) {
    // per-edge-type tables: KefTT[et][k] bf16 (ee@Wk, padded to 16 rows),
    // Vef[et][k] fp32 (ee@Wv), ebuf = ee@Web + beb
    int e = blk - (PH_B + PW_B);
    if (t < 128) {
      float sk = 0.f, sv = 0.f;
      for (int i = 0; i < 128; ++i) {
        float ev = edge_emb[e * 128 + i];
        sk = fmaf(ev, Wk[i * 128 + t], sk);
        sv = fmaf(ev, Wv[i * 128 + t], sv);
      }
      KefTT[e * 128 + t] = f2bf(sk);
      KefTT[(e + 8) * 128 + t] = 0;  // pad cols 8-15
      Vef[e * 128 + t] = sv;
    } else if (t == 128) {
      float s2 = beb[0];
      for (int i = 0; i < 128; ++i) s2 = fmaf(edge_emb[e * 128 + i], Web[i], s2);
      ebuf[e] = s2;
    }
  } else {
    int e = (blk - (PH_B + PW_B + ET_B)) * 256 + t;
    if (e < NE) atomicAdd(&deg[tgt[e]], 1);
  }
}

// ---------------- QKV GEMM via MFMA + MFMA-based qke tail ----------------
// 8 waves: 2 row-groups x 4 col-groups. After staging, waves 0-3 compute
// qke[64 nodes][8 et] = Q_scaled @ KefTT^T + eb via one 16x16x32 MFMA chain each.
__global__ __launch_bounds__(512) void qkv_mfma_kernel(
    const unsigned short* __restrict__ hcat, const unsigned short* __restrict__ WqkvT,
    const float* __restrict__ bq, const float* __restrict__ bk, const float* __restrict__ bv,
    const unsigned short* __restrict__ KefTT, const float* __restrict__ ebuf,
    unsigned short* __restrict__ Qb, unsigned short* __restrict__ KV_u16,
    float* __restrict__ qke) {
  __shared__ unsigned short stage[64][392];
  const int tid = threadIdx.x;
  const int w = tid >> 6, l = tid & 63;
  const int wr = w >> 2, wc = w & 3;
  const int lr = l & 15, lg = l >> 4;
  const int blk = blockIdx.x;

  f32x4 acc[2][6] = {};
  const unsigned short* Ab = hcat + (size_t)(blk * 64 + wr * 32 + lr) * 256 + lg * 8;
  const unsigned short* Bb = WqkvT + (size_t)(wc * 96 + lr) * 128 + lg * 8;
#pragma unroll
  for (int ks = 0; ks < 4; ++ks) {
    bf16x8 a0 = *(const bf16x8*)(Ab + ks * 32);
    bf16x8 a1 = *(const bf16x8*)(Ab + 16 * 256 + ks * 32);
#pragma unroll
    for (int ct = 0; ct < 6; ++ct) {
      bf16x8 b = *(const bf16x8*)(Bb + ct * 16 * 128 + ks * 32);
      acc[0][ct] = __builtin_amdgcn_mfma_f32_16x16x32_bf16(a0, b, acc[0][ct], 0, 0, 0);
      acc[1][ct] = __builtin_amdgcn_mfma_f32_16x16x32_bf16(a1, b, acc[1][ct], 0, 0, 0);
    }
  }
  // bias + scale + convert -> LDS stage in FINAL memory layout:
  //   row u16 layout: [0,128)   = Q col c (scaled by 1/sqrt(128))
  //                   [128,384) = KV interleave: K col j -> 128 + (j>>1)*4 + (j&1)
  //                               V col j -> 128 + (j>>1)*4 + 2 + (j&1)
#pragma unroll
  for (int ct = 0; ct < 6; ++ct) {
    int c = wc * 96 + ct * 16 + lr;
    float bias = (c < 128) ? bq[c] : (c < 256) ? bk[c - 128] : bv[c - 256];
    float sc = (c < 128) ? INVSQ : 1.f;
    int off;
    if (c < 128) off = c;
    else if (c < 256) { int j = c - 128; off = 128 + ((j >> 1) << 2) + (j & 1); }
    else { int j = c - 256; off = 128 + ((j >> 1) << 2) + 2 + (j & 1); }
#pragma unroll
    for (int mt = 0; mt < 2; ++mt)
#pragma unroll
      for (int j = 0; j < 4; ++j)
        stage[wr * 32 + mt * 16 + lg * 4 + j][off] = f2bf((acc[mt][ct][j] + bias) * sc);
  }
  __syncthreads();
  // coalesced 16B stores
  for (int idx = tid; idx < 64 * 48; idx += 512) {
    int r = idx / 48, g = idx % 48;
    int row = blk * 64 + r;
    if (row >= NN) continue;
    u16x8 v = *(const u16x8*)(&stage[r][g * 8]);
    if (g < 16) *(u16x8*)(Qb + (size_t)row * 128 + g * 8) = v;
    else *(u16x8*)(KV_u16 + (size_t)row * 256 + (g - 16) * 8) = v;
  }
  // MFMA qke tail: wave w<4 handles 16 nodes (rows w*16..w*16+15 of stage).
  // A = stage Q rows (bf16, pre-scaled), B = KefTT[col=et][k].
  if (w < 4) {
    f32x4 aq = {0.f, 0.f, 0.f, 0.f};
    const unsigned short* qrow = &stage[w * 16 + lr][0];
    const unsigned short* brow = KefTT + lr * 128;
#pragma unroll
    for (int ks = 0; ks < 4; ++ks) {
      bf16x8 af = *(const bf16x8*)(qrow + lg * 8 + ks * 32);
      bf16x8 bf = *(const bf16x8*)(brow + lg * 8 + ks * 32);
      aq = __builtin_amdgcn_mfma_f32_16x16x32_bf16(af, bf, aq, 0, 0, 0);
    }
    if (lr < 8) {
      float ebv = ebuf[lr];
#pragma unroll
      for (int j = 0; j < 4; ++j) {
        int node = blk * 64 + w * 16 + lg * 4 + j;
        if (node < NN) qke[(size_t)node * 8 + lr] = aq[j] + ebv;
      }
    }
  }
}

// ---------------- CSR build: scans + scatter ----------------
__global__ __launch_bounds__(256) void scan1_kernel(const int* __restrict__ deg,
                                                    int* __restrict__ excl,
                                                    int* __restrict__ sums) {
  __shared__ int buf[256];
  int idx = blockIdx.x * 256 + threadIdx.x;
  int v = (idx < NN) ? deg[idx] : 0;
  buf[threadIdx.x] = v;
  __syncthreads();
  for (int o = 1; o < 256; o <<= 1) {
    int tv = (threadIdx.x >= o) ? buf[threadIdx.x - o] : 0;
    __syncthreads();
    buf[threadIdx.x] += tv;
    __syncthreads();
  }
  if (idx < NN) excl[idx] = buf[threadIdx.x] - v;
  if (threadIdx.x == 255) sums[blockIdx.x] = buf[255];
}

__global__ __launch_bounds__(256) void scan2_kernel(int* __restrict__ sums, int nb) {
  __shared__ int buf[256];
  int v = (threadIdx.x < nb) ? sums[threadIdx.x] : 0;
  buf[threadIdx.x] = v;
  __syncthreads();
  for (int o = 1; o < 256; o <<= 1) {
    int tv = (threadIdx.x >= o) ? buf[threadIdx.x - o] : 0;
    __syncthreads();
    buf[threadIdx.x] += tv;
    __syncthreads();
  }
  if (threadIdx.x < nb) sums[threadIdx.x] = buf[threadIdx.x] - v;  // exclusive
}

__global__ __launch_bounds__(256) void scan3_kernel(const int* __restrict__ excl,
                                                    const int* __restrict__ sums,
                                                    int* __restrict__ row_off,
                                                    int* __restrict__ cursor) {
  int idx = blockIdx.x * 256 + threadIdx.x;
  if (idx < NN) {
    int r = excl[idx] + sums[blockIdx.x];
    row_off[idx] = r;
    cursor[idx] = r;
  }
  if (idx == 0) row_off[NN] = NE;
}

__global__ void scatter_kernel(const int* __restrict__ src, const int* __restrict__ tgt,
                               const int* __restrict__ et, int* __restrict__ cursor,
                               int* __restrict__ packed) {
  int e = blockIdx.x * blockDim.x + threadIdx.x;
  if (e < NE) {
    int pos = atomicAdd(&cursor[tgt[e]], 1);
    packed[pos] = src[e] | (et[e] << 16);  // src < 65536, et < 8
  }
}

// ---------------- attention: one wave/node, 16 lanes/edge, 8 edges in flight --------------
// No-max softmax (logit range ~±8 is safe in fp32). qke folds q·Ke + eb per (node, etype).
__global__ __launch_bounds__(256) void attn_kernel(
    const unsigned short* __restrict__ Qb, const uint4* __restrict__ KV4,
    const float* __restrict__ qke, const float* __restrict__ Vef,
    const int* __restrict__ row_off, const int* __restrict__ packed,
    unsigned short* __restrict__ hcat_u16) {
  const int wid = (blockIdx.x * blockDim.x + threadIdx.x) >> 6;
  const int lane = threadIdx.x & 63;
  const int g = lane >> 4, m = lane & 15;
  const int beg = row_off[wid], end = row_off[wid + 1];
  // q: 8 cols starting 8m (bf16, pre-scaled by 1/sqrt(128))
  u16x8 qv = *(const u16x8*)(Qb + (size_t)wid * 128 + m * 8);
  float q[8];
#pragma unroll
  for (int j = 0; j < 8; ++j) q[j] = bfu(qv[j]);
  const float* qkb = qke + (size_t)wid * 8;
  float a[8] = {0.f, 0.f, 0.f, 0.f, 0.f, 0.f, 0.f, 0.f};
  float s = 0.f;
  for (int i = beg; i < end; i += 8) {
    int iA = i + g, iB = i + 4 + g;
    bool vA = iA < end, vB = iB < end;
    int pA = packed[vA ? iA : beg];
    int pB = packed[vB ? iB : beg];
    int sA = pA & 0xFFFF, eA = pA >> 16;
    int sB = pB & 0xFFFF, eB = pB >> 16;
    // KV row = 32 uint4; lane m reads uint4 2m, 2m+1 (cols 8m..8m+7)
    const uint4* rowA = KV4 + (size_t)sA * 32 + m * 2;
    const uint4* rowB = KV4 + (size_t)sB * 32 + m * 2;
    uint4 xA0 = rowA[0], xA1 = rowA[1];
    uint4 xB0 = rowB[0], xB1 = rowB[1];
    // x: {kpair, vpair, kpair, vpair}
    float dA, dB;
    dA = bf_lo(xA0.x) * q[0];
    dB = bf_lo(xB0.x) * q[0];
    dA = fmaf(bf_hi(xA0.x), q[1], dA);
    dB = fmaf(bf_hi(xB0.x), q[1], dB);
    dA = fmaf(bf_lo(xA0.z), q[2], dA);
    dB = fmaf(bf_lo(xB0.z), q[2], dB);
    dA = fmaf(bf_hi(xA0.z), q[3], dA);
    dB = fmaf(bf_hi(xB0.z), q[3], dB);
    dA = fmaf(bf_lo(xA1.x), q[4], dA);
    dB = fmaf(bf_lo(xB1.x), q[4], dB);
    dA = fmaf(bf_hi(xA1.x), q[5], dA);
    dB = fmaf(bf_hi(xB1.x), q[5], dB);
    dA = fmaf(bf_lo(xA1.z), q[6], dA);
    dB = fmaf(bf_lo(xB1.z), q[6], dB);
    dA = fmaf(bf_hi(xA1.z), q[7], dA);
    dB = fmaf(bf_hi(xB1.z), q[7], dB);
#pragma unroll
    for (int o = 8; o >= 1; o >>= 1) {
      dA += __shfl_xor(dA, o);
      dB += __shfl_xor(dB, o);
    }
    float peA = __expf(dA + qkb[eA]);
    float peB = __expf(dB + qkb[eB]);
    peA = vA ? peA : 0.f;
    peB = vB ? peB : 0.f;
    s += peA + peB;
    const float4* vefA = (const float4*)(Vef + eA * 128 + m * 8);
    const float4* vefB = (const float4*)(Vef + eB * 128 + m * 8);
    float4 vA0 = vefA[0], vA1 = vefA[1];
    float4 vB0 = vefB[0], vB1 = vefB[1];
    a[0] = fmaf(peA, bf_lo(xA0.y) + vA0.x, a[0]);
    a[1] = fmaf(peA, bf_hi(xA0.y) + vA0.y, a[1]);
    a[2] = fmaf(peA, bf_lo(xA0.w) + vA0.z, a[2]);
    a[3] = fmaf(peA, bf_hi(xA0.w) + vA0.w, a[3]);
    a[4] = fmaf(peA, bf_lo(xA1.y) + vA1.x, a[4]);
    a[5] = fmaf(peA, bf_hi(xA1.y) + vA1.y, a[5]);
    a[6] = fmaf(peA, bf_lo(xA1.w) + vA1.z, a[6]);
    a[7] = fmaf(peA, bf_hi(xA1.w) + vA1.w, a[7]);
    a[0] = fmaf(peB, bf_lo(xB0.y) + vB0.x, a[0]);
    a[1] = fmaf(peB, bf_hi(xB0.y) + vB0.y, a[1]);
    a[2] = fmaf(peB, bf_lo(xB0.w) + vB0.z, a[2]);
    a[3] = fmaf(peB, bf_hi(xB0.w) + vB0.w, a[3]);
    a[4] = fmaf(peB, bf_lo(xB1.y) + vB1.x, a[4]);
    a[5] = fmaf(peB, bf_hi(xB1.y) + vB1.y, a[5]);
    a[6] = fmaf(peB, bf_lo(xB1.w) + vB1.z, a[6]);
    a[7] = fmaf(peB, bf_hi(xB1.w) + vB1.w, a[7]);
  }
  // cross-group reduce (xor 16, 32)
#pragma unroll
  for (int o = 16; o <= 32; o <<= 1) {
    s += __shfl_xor(s, o);
#pragma unroll
    for (int j = 0; j < 8; ++j) a[j] += __shfl_xor(a[j], o);
  }
  if (g == 0) {
    float inv = (s > 0.f) ? 1.f / s : 0.f;
    u16x8 o;
#pragma unroll
    for (int j = 0; j < 8; ++j) o[j] = f2bf(a[j] * inv);
    *(u16x8*)(hcat_u16 + (size_t)wid * 256 + 128 + m * 8) = o;
  }
}

// ---------------- FFN + residual + LayerNorm (MFMA, weights in LDS, persistent waves) -------
// 256 blocks x 768 threads (12 waves = 3/SIMD). W1T (64KB) + W2T (32KB) staged once into LDS
// with XOR swizzle (^((row&7)<<4)); per-wave mid buffers (51KB). Total LDS 147KB.
__global__ __launch_bounds__(768) void ffn_mfma_kernel(
    const unsigned short* __restrict__ hcat, const float* __restrict__ hidden,
    const unsigned short* __restrict__ W1T, const unsigned short* __restrict__ W2T,
    const float* __restrict__ b1, const float* __restrict__ b2,
    const float* __restrict__ gamma, const float* __restrict__ beta,
    float* __restrict__ out) {
  __shared__ unsigned short w1s[32768];       // 64KB swizzled [128][256]
  __shared__ unsigned short w2s[16384];       // 32KB swizzled [128][128]
  __shared__ unsigned short mids[12][2176];   // per-wave 16 x 136
  const int tid = threadIdx.x;
  const int w = tid >> 6, l = tid & 63;
  const int lr = l & 15, lg = l >> 4;

  // ---- stage weights (once per block) ----
#pragma unroll
  for (int it = 0; it < 6; ++it) {
    int idx = it * 768 + tid;                // 4096 segs of 8 u16
    if (idx < 4096) {
      int c = idx >> 5, ks8 = idx & 31;
      u16x8 v = *(const u16x8*)(W1T + c * 256 + ks8 * 8);
      int byte = (c * 512 + ks8 * 16) ^ ((c & 7) << 4);
      *(u16x8*)((char*)w1s + byte) = v;
    }
  }
#pragma unroll
  for (int it = 0; it < 3; ++it) {
    int idx = it * 768 + tid;                // 2048 segs
    if (idx < 2048) {
      int c = idx >> 4, ks8 = idx & 15;
      u16x8 v = *(const u16x8*)(W2T + c * 128 + ks8 * 8);
      int byte = (c * 256 + ks8 * 16) ^ ((c & 7) << 4);
      *(u16x8*)((char*)w2s + byte) = v;
    }
  }
  __syncthreads();

  // ---- per-lane constants ----
  float bias1[8], bias2[8], ga[8], be[8];
#pragma unroll
  for (int ct = 0; ct < 8; ++ct) {
    int c = ct * 16 + lr;
    bias1[ct] = b1[c];
    bias2[ct] = b2[c];
    ga[ct] = gamma[c];
    be[ct] = beta[c];
  }
  unsigned short* midw = mids[w];
  const char* w1b = (const char*)w1s;
  const char* w2b = (const char*)w2s;

  for (int t = blockIdx.x * 12 + w; t < NTILES; t += 3072) {
    // A fragments (K=256): 8 x 16B from hcat
    const unsigned short* Ab = hcat + (size_t)(t * 16 + lr) * 256 + lg * 8;
    bf16x8 a[8];
#pragma unroll
    for (int ks = 0; ks < 8; ++ks) a[ks] = *(const bf16x8*)(Ab + ks * 32);

    // GEMM1: K=256 -> 128, B from LDS
    f32x4 acc[8] = {};
#pragma unroll
    for (int ks = 0; ks < 8; ++ks) {
#pragma unroll
      for (int ct = 0; ct < 8; ++ct) {
        int byte = ((ct * 16 + lr) * 512 + (lg * 8 + ks * 32) * 2) ^ ((lr & 7) << 4);
        bf16x8 b = *(const bf16x8*)(w1b + byte);
        acc[ct] = __builtin_amdgcn_mfma_f32_16x16x32_bf16(a[ks], b, acc[ct], 0, 0, 0);
      }
    }

    // residual prefetch (consumed in epilogue; latency hidden under GEMM2)
    float res[8][4];
#pragma unroll
    for (int ct = 0; ct < 8; ++ct)
#pragma unroll
      for (int j = 0; j < 4; ++j) {
        int r = t * 16 + lg * 4 + j;
        res[ct][j] = (r < NN) ? hidden[(size_t)r * 128 + ct * 16 + lr] : 0.f;
      }

    // silu -> per-wave mid buffer
#pragma unroll
    for (int ct = 0; ct < 8; ++ct) {
      float bb = bias1[ct];
#pragma unroll
      for (int j = 0; j < 4; ++j) {
        float x = acc[ct][j] + bb;
        float sl = x / (1.f + __expf(-x));
        midw[(lg * 4 + j) * 136 + ct * 16 + lr] = f2bf(sl);
      }
    }
    asm volatile("s_waitcnt lgkmcnt(0)" ::: "memory");
    __builtin_amdgcn_sched_barrier(0);

    // GEMM2: K=128 -> 128, A from mid, B from LDS
    f32x4 acc2[8] = {};
#pragma unroll
    for (int ks = 0; ks < 4; ++ks) {
      bf16x8 a2 = *(const bf16x8*)(midw + lr * 136 + lg * 8 + ks * 32);
#pragma unroll
      for (int ct = 0; ct < 8; ++ct) {
        int byte = ((ct * 16 + lr) * 256 + (lg * 8 + ks * 32) * 2) ^ ((lr & 7) << 4);
        bf16x8 b = *(const bf16x8*)(w2b + byte);
        acc2[ct] = __builtin_amdgcn_mfma_f32_16x16x32_bf16(a2, b, acc2[ct], 0, 0, 0);
      }
    }

    // epilogue: + b2 + residual, LayerNorm, store
    float x[8][4];
#pragma unroll
    for (int ct = 0; ct < 8; ++ct)
#pragma unroll
      for (int j = 0; j < 4; ++j) x[ct][j] = acc2[ct][j] + bias2[ct] + res[ct][j];
#pragma unroll
    for (int j = 0; j < 4; ++j) {
      float s = 0.f, ss = 0.f;
#pragma unroll
      for (int ct = 0; ct < 8; ++ct) {
        s += x[ct][j];
        ss += x[ct][j] * x[ct][j];
      }
#pragma unroll
      for (int o = 8; o >= 1; o >>= 1) {
        s += __shfl_xor(s, o);
        ss += __shfl_xor(ss, o);
      }
      float mu = s * (1.f / 128.f);
      float inv = rsqrtf(ss * (1.f / 128.f) - mu * mu + EPS);
      int r = t * 16 + lg * 4 + j;
      if (r < NN) {
#pragma unroll
        for (int ct = 0; ct < 8; ++ct) {
          int c = ct * 16 + lr;
          out[(size_t)r * 128 + c] = (x[ct][j] - mu) * inv * ga[ct] + be[ct];
        }
      }
    }
  }
}

extern "C" void kernel_launch(void* const* d_in, const int* in_sizes, int n_in,
                              void* d_out, int out_size, void* d_ws, size_t ws_size,
                              hipStream_t stream) {
  const float* hidden = (const float*)d_in[0];
  const int* edge_index = (const int*)d_in[1];
  const int* edge_type = (const int*)d_in[2];
  const float* edge_emb = (const float*)d_in[3];
  const float* Wq = (const float*)d_in[4];
  const float* bq = (const float*)d_in[5];
  const float* Wk = (const float*)d_in[6];
  const float* bk = (const float*)d_in[7];
  const float* Wv = (const float*)d_in[8];
  const float* bv = (const float*)d_in[9];
  const float* Web = (const float*)d_in[10];
  const float* beb = (const float*)d_in[11];
  const float* W1 = (const float*)d_in[12];
  const float* b1 = (const float*)d_in[13];
  const float* W2 = (const float*)d_in[14];
  const float* b2 = (const float*)d_in[15];
  const float* gamma = (const float*)d_in[16];
  const float* beta = (const float*)d_in[17];
  float* out = (float*)d_out;

  const int* srcp = edge_index;
  const int* tgtp = edge_index + NE;

  size_t off = 0;
  auto alloc = [&](size_t bytes) {
    void* p = (char*)d_ws + off;
    off += (bytes + 255) & ~(size_t)255;
    return p;
  };
  unsigned short* hcat = (unsigned short*)alloc((size_t)NPAD * 256 * 2);  // [h|agg] bf16
  unsigned short* Qb = (unsigned short*)alloc((size_t)NPAD * 128 * 2);    // pre-scaled
  unsigned short* KV = (unsigned short*)alloc((size_t)NPAD * 256 * 2);    // interleaved k/v pairs
  unsigned short* WqkvT = (unsigned short*)alloc(384 * 128 * 2);
  unsigned short* W1T = (unsigned short*)alloc(128 * 256 * 2);
  unsigned short* W2T = (unsigned short*)alloc(128 * 128 * 2);
  unsigned short* KefTT = (unsigned short*)alloc(16 * 128 * 2);  // bf16 Kef^T (padded to 16)
  float* Vef = (float*)alloc(ET * H * 4);
  float* ebuf = (float*)alloc(ET * 4);
  float* qke = (float*)alloc((size_t)NN * 8 * 4);
  int* deg = (int*)alloc((size_t)NN * 4);
  int* excl = (int*)alloc((size_t)NN * 4);
  int* sums = (int*)alloc(256 * 4);
  int* row_off = (int*)alloc((size_t)(NN + 1) * 4);
  int* cursor = (int*)alloc((size_t)NN * 4);
  int* packed = (int*)alloc((size_t)NE * 4);

  hipMemsetAsync(deg, 0, (size_t)NN * 4, stream);

  const int scan_blocks = (NN + 255) / 256;  // 196

  prep_all_kernel<<<PH_B + PW_B + ET_B + HIST_B, 256, 0, stream>>>(
      hidden, edge_emb, Wq, Wk, Wv, W1, W2, Web, beb, tgtp, hcat, WqkvT, W1T, W2T, KefTT, Vef,
      ebuf, deg);
  scan1_kernel<<<scan_blocks, 256, 0, stream>>>(deg, excl, sums);
  scan2_kernel<<<1, 256, 0, stream>>>(sums, scan_blocks);
  scan3_kernel<<<scan_blocks, 256, 0, stream>>>(excl, sums, row_off, cursor);
  scatter_kernel<<<(NE + 255) / 256, 256, 0, stream>>>(srcp, tgtp, edge_type, cursor, packed);
  qkv_mfma_kernel<<<NPAD / 64, 512, 0, stream>>>(hcat, WqkvT, bq, bk, bv, KefTT, ebuf, Qb, KV,
                                                 qke);
  attn_kernel<<<(NN * 64) / 256, 256, 0, stream>>>(Qb, (const uint4*)KV, qke, Vef, row_off,
                                                   packed, hcat);
  ffn_mfma_kernel<<<256, 768, 0, stream>>>(hcat, hidden, W1T, W2T, b1, b2, gamma, beta, out);
}

// Round 12
// 283.303 us; speedup vs baseline: 1.2032x; 1.1450x over previous
//
#include <hip/hip_runtime.h>
#include <math.h>

#define NN 50000
#define NPAD 50048      // 782 * 64
#define NTILES 3128     // NPAD / 16
#define NE 600000
#define H 128
#define ET 8
#define EPS 1e-5f
#define INVSQ 0.08838834764831845f  // 1/sqrt(128)

typedef __attribute__((ext_vector_type(8))) short bf16x8;
typedef __attribute__((ext_vector_type(8))) unsigned short u16x8;
typedef __attribute__((ext_vector_type(4))) float f32x4;

static __device__ inline float bf_lo(unsigned int w) { return __uint_as_float(w << 16); }
static __device__ inline float bf_hi(unsigned int w) { return __uint_as_float(w & 0xFFFF0000u); }
static __device__ inline float bfu(unsigned short v) {
  return __uint_as_float((unsigned int)v << 16);
}
static __device__ inline unsigned short f2bf(float f) {
  unsigned int u = __float_as_uint(f);
  return (unsigned short)((u + 0x7FFFu + ((u >> 16) & 1u)) >> 16);  // RNE
}

// ================= fused prep: hidden->bf16, weights->bf16^T, etype tables, degree hist =======
#define PH_B 3125
#define PW_B 384
#define ET_B 8
#define HIST_B 2344

__global__ __launch_bounds__(256) void prep_all_kernel(
    const float* __restrict__ hidden, const float* __restrict__ edge_emb,
    const float* __restrict__ Wq, const float* __restrict__ Wk, const float* __restrict__ Wv,
    const float* __restrict__ W1, const float* __restrict__ W2,
    const float* __restrict__ Web, const float* __restrict__ beb,
    const int* __restrict__ tgt,
    unsigned short* __restrict__ hcat, unsigned short* __restrict__ WqkvT,
    unsigned short* __restrict__ W1T, unsigned short* __restrict__ W2T,
    unsigned short* __restrict__ KefTT, float* __restrict__ Vef, float* __restrict__ ebuf,
    int* __restrict__ deg) {
  const int blk = blockIdx.x;
  const int t = threadIdx.x;
  if (blk < PH_B) {
    // hidden fp32 -> bf16 into hcat[:, 0:128] (row stride 256)
    int g = blk * 256 + t;  // NN*16 = 800000 exactly
    int row = g >> 4, seg = g & 15;
    const float4* src = (const float4*)(hidden + (size_t)row * 128 + seg * 8);
    float4 x0 = src[0], x1 = src[1];
    u16x8 o;
    o[0] = f2bf(x0.x); o[1] = f2bf(x0.y); o[2] = f2bf(x0.z); o[3] = f2bf(x0.w);
    o[4] = f2bf(x1.x); o[5] = f2bf(x1.y); o[6] = f2bf(x1.z); o[7] = f2bf(x1.w);
    *(u16x8*)(hcat + (size_t)row * 256 + seg * 8) = o;
  } else if (blk < PH_B + PW_B) {
    int idx = (blk - PH_B) * 256 + t;
    if (idx < 49152) {
      int r = idx >> 7, k = idx & 127;
      const float* W = (r < 128) ? Wq : (r < 256) ? Wk : Wv;
      WqkvT[idx] = f2bf(W[k * 128 + (r & 127)]);
    } else if (idx < 81920) {
      int j = idx - 49152;
      int r = j >> 8, k = j & 255;
      W1T[j] = f2bf(W1[k * 128 + r]);
    } else if (idx < 98304) {
      int j = idx - 81920;
      int r = j >> 7, k = j & 127;
      W2T[j] = f2bf(W2[k * 128 + r]);
    }
  } else if (blk < PH_B + PW_B + ET_B) {
    // per-edge-type tables: KefTT[et][k] bf16 (ee@Wk, padded to 16 rows),
    // Vef[et][k] fp32 (ee@Wv), ebuf = ee@Web + beb
    int e = blk - (PH_B + PW_B);
    if (t < 128) {
      float sk = 0.f, sv = 0.f;
      for (int i = 0; i < 128; ++i) {
        float ev = edge_emb[e * 128 + i];
        sk = fmaf(ev, Wk[i * 128 + t], sk);
        sv = fmaf(ev, Wv[i * 128 + t], sv);
      }
      KefTT[e * 128 + t] = f2bf(sk);
      KefTT[(e + 8) * 128 + t] = 0;  // pad cols 8-15
      Vef[e * 128 + t] = sv;
    } else if (t == 128) {
      float s2 = beb[0];
      for (int i = 0; i < 128; ++i) s2 = fmaf(edge_emb[e * 128 + i], Web[i], s2);
      ebuf[e] = s2;
    }
  } else {
    int e = (blk - (PH_B + PW_B + ET_B)) * 256 + t;
    if (e < NE) atomicAdd(&deg[tgt[e]], 1);
  }
}

// ---------------- QKV GEMM via MFMA + MFMA-based qke tail ----------------
// 8 waves: 2 row-groups x 4 col-groups. After staging, waves 0-3 compute
// qke[64 nodes][8 et] = Q_scaled @ KefTT^T + eb via one 16x16x32 MFMA chain each.
__global__ __launch_bounds__(512) void qkv_mfma_kernel(
    const unsigned short* __restrict__ hcat, const unsigned short* __restrict__ WqkvT,
    const float* __restrict__ bq, const float* __restrict__ bk, const float* __restrict__ bv,
    const unsigned short* __restrict__ KefTT, const float* __restrict__ ebuf,
    unsigned short* __restrict__ Qb, unsigned short* __restrict__ KV_u16,
    float* __restrict__ qke) {
  __shared__ unsigned short stage[64][392];
  const int tid = threadIdx.x;
  const int w = tid >> 6, l = tid & 63;
  const int wr = w >> 2, wc = w & 3;
  const int lr = l & 15, lg = l >> 4;
  const int blk = blockIdx.x;

  f32x4 acc[2][6] = {};
  const unsigned short* Ab = hcat + (size_t)(blk * 64 + wr * 32 + lr) * 256 + lg * 8;
  const unsigned short* Bb = WqkvT + (size_t)(wc * 96 + lr) * 128 + lg * 8;
#pragma unroll
  for (int ks = 0; ks < 4; ++ks) {
    bf16x8 a0 = *(const bf16x8*)(Ab + ks * 32);
    bf16x8 a1 = *(const bf16x8*)(Ab + 16 * 256 + ks * 32);
#pragma unroll
    for (int ct = 0; ct < 6; ++ct) {
      bf16x8 b = *(const bf16x8*)(Bb + ct * 16 * 128 + ks * 32);
      acc[0][ct] = __builtin_amdgcn_mfma_f32_16x16x32_bf16(a0, b, acc[0][ct], 0, 0, 0);
      acc[1][ct] = __builtin_amdgcn_mfma_f32_16x16x32_bf16(a1, b, acc[1][ct], 0, 0, 0);
    }
  }
  // bias + scale + convert -> LDS stage in FINAL memory layout:
  //   row u16 layout: [0,128)   = Q col c (scaled by 1/sqrt(128))
  //                   [128,384) = KV interleave: K col j -> 128 + (j>>1)*4 + (j&1)
  //                               V col j -> 128 + (j>>1)*4 + 2 + (j&1)
#pragma unroll
  for (int ct = 0; ct < 6; ++ct) {
    int c = wc * 96 + ct * 16 + lr;
    float bias = (c < 128) ? bq[c] : (c < 256) ? bk[c - 128] : bv[c - 256];
    float sc = (c < 128) ? INVSQ : 1.f;
    int off;
    if (c < 128) off = c;
    else if (c < 256) { int j = c - 128; off = 128 + ((j >> 1) << 2) + (j & 1); }
    else { int j = c - 256; off = 128 + ((j >> 1) << 2) + 2 + (j & 1); }
#pragma unroll
    for (int mt = 0; mt < 2; ++mt)
#pragma unroll
      for (int j = 0; j < 4; ++j)
        stage[wr * 32 + mt * 16 + lg * 4 + j][off] = f2bf((acc[mt][ct][j] + bias) * sc);
  }
  __syncthreads();
  // coalesced 16B stores
  for (int idx = tid; idx < 64 * 48; idx += 512) {
    int r = idx / 48, g = idx % 48;
    int row = blk * 64 + r;
    if (row >= NN) continue;
    u16x8 v = *(const u16x8*)(&stage[r][g * 8]);
    if (g < 16) *(u16x8*)(Qb + (size_t)row * 128 + g * 8) = v;
    else *(u16x8*)(KV_u16 + (size_t)row * 256 + (g - 16) * 8) = v;
  }
  // MFMA qke tail: wave w<4 handles 16 nodes (rows w*16..w*16+15 of stage).
  // A = stage Q rows (bf16, pre-scaled), B = KefTT[col=et][k].
  if (w < 4) {
    f32x4 aq = {0.f, 0.f, 0.f, 0.f};
    const unsigned short* qrow = &stage[w * 16 + lr][0];
    const unsigned short* brow = KefTT + lr * 128;
#pragma unroll
    for (int ks = 0; ks < 4; ++ks) {
      bf16x8 af = *(const bf16x8*)(qrow + lg * 8 + ks * 32);
      bf16x8 bf = *(const bf16x8*)(brow + lg * 8 + ks * 32);
      aq = __builtin_amdgcn_mfma_f32_16x16x32_bf16(af, bf, aq, 0, 0, 0);
    }
    if (lr < 8) {
      float ebv = ebuf[lr];
#pragma unroll
      for (int j = 0; j < 4; ++j) {
        int node = blk * 64 + w * 16 + lg * 4 + j;
        if (node < NN) qke[(size_t)node * 8 + lr] = aq[j] + ebv;
      }
    }
  }
}

// ---------------- CSR build: scans + scatter ----------------
__global__ __launch_bounds__(256) void scan1_kernel(const int* __restrict__ deg,
                                                    int* __restrict__ excl,
                                                    int* __restrict__ sums) {
  __shared__ int buf[256];
  int idx = blockIdx.x * 256 + threadIdx.x;
  int v = (idx < NN) ? deg[idx] : 0;
  buf[threadIdx.x] = v;
  __syncthreads();
  for (int o = 1; o < 256; o <<= 1) {
    int tv = (threadIdx.x >= o) ? buf[threadIdx.x - o] : 0;
    __syncthreads();
    buf[threadIdx.x] += tv;
    __syncthreads();
  }
  if (idx < NN) excl[idx] = buf[threadIdx.x] - v;
  if (threadIdx.x == 255) sums[blockIdx.x] = buf[255];
}

__global__ __launch_bounds__(256) void scan2_kernel(int* __restrict__ sums, int nb) {
  __shared__ int buf[256];
  int v = (threadIdx.x < nb) ? sums[threadIdx.x] : 0;
  buf[threadIdx.x] = v;
  __syncthreads();
  for (int o = 1; o < 256; o <<= 1) {
    int tv = (threadIdx.x >= o) ? buf[threadIdx.x - o] : 0;
    __syncthreads();
    buf[threadIdx.x] += tv;
    __syncthreads();
  }
  if (threadIdx.x < nb) sums[threadIdx.x] = buf[threadIdx.x] - v;  // exclusive
}

__global__ __launch_bounds__(256) void scan3_kernel(const int* __restrict__ excl,
                                                    const int* __restrict__ sums,
                                                    int* __restrict__ row_off,
                                                    int* __restrict__ cursor) {
  int idx = blockIdx.x * 256 + threadIdx.x;
  if (idx < NN) {
    int r = excl[idx] + sums[blockIdx.x];
    row_off[idx] = r;
    cursor[idx] = r;
  }
  if (idx == 0) row_off[NN] = NE;
}

__global__ void scatter_kernel(const int* __restrict__ src, const int* __restrict__ tgt,
                               const int* __restrict__ et, int* __restrict__ cursor,
                               int* __restrict__ packed) {
  int e = blockIdx.x * blockDim.x + threadIdx.x;
  if (e < NE) {
    int pos = atomicAdd(&cursor[tgt[e]], 1);
    packed[pos] = src[e] | (et[e] << 16);  // src < 65536, et < 8
  }
}

// ---------------- attention: one wave/node, 16 lanes/edge, 8 edges in flight --------------
// No-max softmax (logit range ~±8 is safe in fp32). qke folds q·Ke + eb per (node, etype).
__global__ __launch_bounds__(256) void attn_kernel(
    const unsigned short* __restrict__ Qb, const uint4* __restrict__ KV4,
    const float* __restrict__ qke, const float* __restrict__ Vef,
    const int* __restrict__ row_off, const int* __restrict__ packed,
    unsigned short* __restrict__ hcat_u16) {
  const int wid = (blockIdx.x * blockDim.x + threadIdx.x) >> 6;
  const int lane = threadIdx.x & 63;
  const int g = lane >> 4, m = lane & 15;
  const int beg = row_off[wid], end = row_off[wid + 1];
  // q: 8 cols starting 8m (bf16, pre-scaled by 1/sqrt(128))
  u16x8 qv = *(const u16x8*)(Qb + (size_t)wid * 128 + m * 8);
  float q[8];
#pragma unroll
  for (int j = 0; j < 8; ++j) q[j] = bfu(qv[j]);
  const float* qkb = qke + (size_t)wid * 8;
  float a[8] = {0.f, 0.f, 0.f, 0.f, 0.f, 0.f, 0.f, 0.f};
  float s = 0.f;
  for (int i = beg; i < end; i += 8) {
    int iA = i + g, iB = i + 4 + g;
    bool vA = iA < end, vB = iB < end;
    int pA = packed[vA ? iA : beg];
    int pB = packed[vB ? iB : beg];
    int sA = pA & 0xFFFF, eA = pA >> 16;
    int sB = pB & 0xFFFF, eB = pB >> 16;
    // KV row = 32 uint4; lane m reads uint4 2m, 2m+1 (cols 8m..8m+7)
    const uint4* rowA = KV4 + (size_t)sA * 32 + m * 2;
    const uint4* rowB = KV4 + (size_t)sB * 32 + m * 2;
    uint4 xA0 = rowA[0], xA1 = rowA[1];
    uint4 xB0 = rowB[0], xB1 = rowB[1];
    // x: {kpair, vpair, kpair, vpair}
    float dA, dB;
    dA = bf_lo(xA0.x) * q[0];
    dB = bf_lo(xB0.x) * q[0];
    dA = fmaf(bf_hi(xA0.x), q[1], dA);
    dB = fmaf(bf_hi(xB0.x), q[1], dB);
    dA = fmaf(bf_lo(xA0.z), q[2], dA);
    dB = fmaf(bf_lo(xB0.z), q[2], dB);
    dA = fmaf(bf_hi(xA0.z), q[3], dA);
    dB = fmaf(bf_hi(xB0.z), q[3], dB);
    dA = fmaf(bf_lo(xA1.x), q[4], dA);
    dB = fmaf(bf_lo(xB1.x), q[4], dB);
    dA = fmaf(bf_hi(xA1.x), q[5], dA);
    dB = fmaf(bf_hi(xB1.x), q[5], dB);
    dA = fmaf(bf_lo(xA1.z), q[6], dA);
    dB = fmaf(bf_lo(xB1.z), q[6], dB);
    dA = fmaf(bf_hi(xA1.z), q[7], dA);
    dB = fmaf(bf_hi(xB1.z), q[7], dB);
#pragma unroll
    for (int o = 8; o >= 1; o >>= 1) {
      dA += __shfl_xor(dA, o);
      dB += __shfl_xor(dB, o);
    }
    float peA = __expf(dA + qkb[eA]);
    float peB = __expf(dB + qkb[eB]);
    peA = vA ? peA : 0.f;
    peB = vB ? peB : 0.f;
    s += peA + peB;
    const float4* vefA = (const float4*)(Vef + eA * 128 + m * 8);
    const float4* vefB = (const float4*)(Vef + eB * 128 + m * 8);
    float4 vA0 = vefA[0], vA1 = vefA[1];
    float4 vB0 = vefB[0], vB1 = vefB[1];
    a[0] = fmaf(peA, bf_lo(xA0.y) + vA0.x, a[0]);
    a[1] = fmaf(peA, bf_hi(xA0.y) + vA0.y, a[1]);
    a[2] = fmaf(peA, bf_lo(xA0.w) + vA0.z, a[2]);
    a[3] = fmaf(peA, bf_hi(xA0.w) + vA0.w, a[3]);
    a[4] = fmaf(peA, bf_lo(xA1.y) + vA1.x, a[4]);
    a[5] = fmaf(peA, bf_hi(xA1.y) + vA1.y, a[5]);
    a[6] = fmaf(peA, bf_lo(xA1.w) + vA1.z, a[6]);
    a[7] = fmaf(peA, bf_hi(xA1.w) + vA1.w, a[7]);
    a[0] = fmaf(peB, bf_lo(xB0.y) + vB0.x, a[0]);
    a[1] = fmaf(peB, bf_hi(xB0.y) + vB0.y, a[1]);
    a[2] = fmaf(peB, bf_lo(xB0.w) + vB0.z, a[2]);
    a[3] = fmaf(peB, bf_hi(xB0.w) + vB0.w, a[3]);
    a[4] = fmaf(peB, bf_lo(xB1.y) + vB1.x, a[4]);
    a[5] = fmaf(peB, bf_hi(xB1.y) + vB1.y, a[5]);
    a[6] = fmaf(peB, bf_lo(xB1.w) + vB1.z, a[6]);
    a[7] = fmaf(peB, bf_hi(xB1.w) + vB1.w, a[7]);
  }
  // cross-group reduce (xor 16, 32)
#pragma unroll
  for (int o = 16; o <= 32; o <<= 1) {
    s += __shfl_xor(s, o);
#pragma unroll
    for (int j = 0; j < 8; ++j) a[j] += __shfl_xor(a[j], o);
  }
  if (g == 0) {
    float inv = (s > 0.f) ? 1.f / s : 0.f;
    u16x8 o;
#pragma unroll
    for (int j = 0; j < 8; ++j) o[j] = f2bf(a[j] * inv);
    *(u16x8*)(hcat_u16 + (size_t)wid * 256 + 128 + m * 8) = o;
  }
}

// ---------------- FFN + residual + LayerNorm (MFMA, weights in LDS, persistent waves) -------
// 256 blocks x 512 threads (8 waves = 2/SIMD, up to 256 VGPR -> no spills). W1T (64KB) +
// W2T (32KB) staged once into LDS with XOR swizzle; per-wave mid buffers. LDS 130KB.
__global__ __launch_bounds__(512) void ffn_mfma_kernel(
    const unsigned short* __restrict__ hcat, const float* __restrict__ hidden,
    const unsigned short* __restrict__ W1T, const unsigned short* __restrict__ W2T,
    const float* __restrict__ b1, const float* __restrict__ b2,
    const float* __restrict__ gamma, const float* __restrict__ beta,
    float* __restrict__ out) {
  __shared__ unsigned short w1s[32768];      // 64KB swizzled [128][256]
  __shared__ unsigned short w2s[16384];      // 32KB swizzled [128][128]
  __shared__ unsigned short mids[8][2176];   // per-wave 16 x 136
  const int tid = threadIdx.x;
  const int w = tid >> 6, l = tid & 63;
  const int lr = l & 15, lg = l >> 4;

  // ---- stage weights (once per block) ----
#pragma unroll
  for (int it = 0; it < 8; ++it) {
    int idx = it * 512 + tid;                // 4096 segs of 8 u16
    int c = idx >> 5, ks8 = idx & 31;
    u16x8 v = *(const u16x8*)(W1T + c * 256 + ks8 * 8);
    int byte = (c * 512 + ks8 * 16) ^ ((c & 7) << 4);
    *(u16x8*)((char*)w1s + byte) = v;
  }
#pragma unroll
  for (int it = 0; it < 4; ++it) {
    int idx = it * 512 + tid;                // 2048 segs
    int c = idx >> 4, ks8 = idx & 15;
    u16x8 v = *(const u16x8*)(W2T + c * 128 + ks8 * 8);
    int byte = (c * 256 + ks8 * 16) ^ ((c & 7) << 4);
    *(u16x8*)((char*)w2s + byte) = v;
  }
  __syncthreads();

  // ---- per-lane constants ----
  float bias1[8], bias2[8], ga[8], be[8];
#pragma unroll
  for (int ct = 0; ct < 8; ++ct) {
    int c = ct * 16 + lr;
    bias1[ct] = b1[c];
    bias2[ct] = b2[c];
    ga[ct] = gamma[c];
    be[ct] = beta[c];
  }
  unsigned short* midw = mids[w];
  const char* w1b = (const char*)w1s;
  const char* w2b = (const char*)w2s;

  for (int t = blockIdx.x * 8 + w; t < NTILES; t += 2048) {
    // A fragments (K=256): 8 x 16B from hcat
    const unsigned short* Ab = hcat + (size_t)(t * 16 + lr) * 256 + lg * 8;
    bf16x8 a[8];
#pragma unroll
    for (int ks = 0; ks < 8; ++ks) a[ks] = *(const bf16x8*)(Ab + ks * 32);

    // GEMM1: K=256 -> 128, B from LDS
    f32x4 acc[8] = {};
#pragma unroll
    for (int ks = 0; ks < 8; ++ks) {
#pragma unroll
      for (int ct = 0; ct < 8; ++ct) {
        int byte = ((ct * 16 + lr) * 512 + (lg * 8 + ks * 32) * 2) ^ ((lr & 7) << 4);
        bf16x8 b = *(const bf16x8*)(w1b + byte);
        acc[ct] = __builtin_amdgcn_mfma_f32_16x16x32_bf16(a[ks], b, acc[ct], 0, 0, 0);
      }
    }

    // residual prefetch (consumed in epilogue; latency hidden under GEMM2)
    float res[8][4];
#pragma unroll
    for (int ct = 0; ct < 8; ++ct)
#pragma unroll
      for (int j = 0; j < 4; ++j) {
        int r = t * 16 + lg * 4 + j;
        res[ct][j] = (r < NN) ? hidden[(size_t)r * 128 + ct * 16 + lr] : 0.f;
      }

    // silu -> per-wave mid buffer
#pragma unroll
    for (int ct = 0; ct < 8; ++ct) {
      float bb = bias1[ct];
#pragma unroll
      for (int j = 0; j < 4; ++j) {
        float x = acc[ct][j] + bb;
        float sl = x / (1.f + __expf(-x));
        midw[(lg * 4 + j) * 136 + ct * 16 + lr] = f2bf(sl);
      }
    }
    asm volatile("s_waitcnt lgkmcnt(0)" ::: "memory");
    __builtin_amdgcn_sched_barrier(0);

    // GEMM2: K=128 -> 128, A from mid, B from LDS
    f32x4 acc2[8] = {};
#pragma unroll
    for (int ks = 0; ks < 4; ++ks) {
      bf16x8 a2 = *(const bf16x8*)(midw + lr * 136 + lg * 8 + ks * 32);
#pragma unroll
      for (int ct = 0; ct < 8; ++ct) {
        int byte = ((ct * 16 + lr) * 256 + (lg * 8 + ks * 32) * 2) ^ ((lr & 7) << 4);
        bf16x8 b = *(const bf16x8*)(w2b + byte);
        acc2[ct] = __builtin_amdgcn_mfma_f32_16x16x32_bf16(a2, b, acc2[ct], 0, 0, 0);
      }
    }

    // epilogue: + b2 + residual, LayerNorm, store
    float x[8][4];
#pragma unroll
    for (int ct = 0; ct < 8; ++ct)
#pragma unroll
      for (int j = 0; j < 4; ++j) x[ct][j] = acc2[ct][j] + bias2[ct] + res[ct][j];
#pragma unroll
    for (int j = 0; j < 4; ++j) {
      float s = 0.f, ss = 0.f;
#pragma unroll
      for (int ct = 0; ct < 8; ++ct) {
        s += x[ct][j];
        ss += x[ct][j] * x[ct][j];
      }
#pragma unroll
      for (int o = 8; o >= 1; o >>= 1) {
        s += __shfl_xor(s, o);
        ss += __shfl_xor(ss, o);
      }
      float mu = s * (1.f / 128.f);
      float inv = rsqrtf(ss * (1.f / 128.f) - mu * mu + EPS);
      int r = t * 16 + lg * 4 + j;
      if (r < NN) {
#pragma unroll
        for (int ct = 0; ct < 8; ++ct) {
          int c = ct * 16 + lr;
          out[(size_t)r * 128 + c] = (x[ct][j] - mu) * inv * ga[ct] + be[ct];
        }
      }
    }
  }
}

extern "C" void kernel_launch(void* const* d_in, const int* in_sizes, int n_in,
                              void* d_out, int out_size, void* d_ws, size_t ws_size,
                              hipStream_t stream) {
  const float* hidden = (const float*)d_in[0];
  const int* edge_index = (const int*)d_in[1];
  const int* edge_type = (const int*)d_in[2];
  const float* edge_emb = (const float*)d_in[3];
  const float* Wq = (const float*)d_in[4];
  const float* bq = (const float*)d_in[5];
  const float* Wk = (const float*)d_in[6];
  const float* bk = (const float*)d_in[7];
  const float* Wv = (const float*)d_in[8];
  const float* bv = (const float*)d_in[9];
  const float* Web = (const float*)d_in[10];
  const float* beb = (const float*)d_in[11];
  const float* W1 = (const float*)d_in[12];
  const float* b1 = (const float*)d_in[13];
  const float* W2 = (const float*)d_in[14];
  const float* b2 = (const float*)d_in[15];
  const float* gamma = (const float*)d_in[16];
  const float* beta = (const float*)d_in[17];
  float* out = (float*)d_out;

  const int* srcp = edge_index;
  const int* tgtp = edge_index + NE;

  size_t off = 0;
  auto alloc = [&](size_t bytes) {
    void* p = (char*)d_ws + off;
    off += (bytes + 255) & ~(size_t)255;
    return p;
  };
  unsigned short* hcat = (unsigned short*)alloc((size_t)NPAD * 256 * 2);  // [h|agg] bf16
  unsigned short* Qb = (unsigned short*)alloc((size_t)NPAD * 128 * 2);    // pre-scaled
  unsigned short* KV = (unsigned short*)alloc((size_t)NPAD * 256 * 2);    // interleaved k/v pairs
  unsigned short* WqkvT = (unsigned short*)alloc(384 * 128 * 2);
  unsigned short* W1T = (unsigned short*)alloc(128 * 256 * 2);
  unsigned short* W2T = (unsigned short*)alloc(128 * 128 * 2);
  unsigned short* KefTT = (unsigned short*)alloc(16 * 128 * 2);  // bf16 Kef^T (padded to 16)
  float* Vef = (float*)alloc(ET * H * 4);
  float* ebuf = (float*)alloc(ET * 4);
  float* qke = (float*)alloc((size_t)NN * 8 * 4);
  int* deg = (int*)alloc((size_t)NN * 4);
  int* excl = (int*)alloc((size_t)NN * 4);
  int* sums = (int*)alloc(256 * 4);
  int* row_off = (int*)alloc((size_t)(NN + 1) * 4);
  int* cursor = (int*)alloc((size_t)NN * 4);
  int* packed = (int*)alloc((size_t)NE * 4);

  hipMemsetAsync(deg, 0, (size_t)NN * 4, stream);

  const int scan_blocks = (NN + 255) / 256;  // 196

  prep_all_kernel<<<PH_B + PW_B + ET_B + HIST_B, 256, 0, stream>>>(
      hidden, edge_emb, Wq, Wk, Wv, W1, W2, Web, beb, tgtp, hcat, WqkvT, W1T, W2T, KefTT, Vef,
      ebuf, deg);
  scan1_kernel<<<scan_blocks, 256, 0, stream>>>(deg, excl, sums);
  scan2_kernel<<<1, 256, 0, stream>>>(sums, scan_blocks);
  scan3_kernel<<<scan_blocks, 256, 0, stream>>>(excl, sums, row_off, cursor);
  scatter_kernel<<<(NE + 255) / 256, 256, 0, stream>>>(srcp, tgtp, edge_type, cursor, packed);
  qkv_mfma_kernel<<<NPAD / 64, 512, 0, stream>>>(hcat, WqkvT, bq, bk, bv, KefTT, ebuf, Qb, KV,
                                                 qke);
  attn_kernel<<<(NN * 64) / 256, 256, 0, stream>>>(Qb, (const uint4*)KV, qke, Vef, row_off,
                                                   packed, hcat);
  ffn_mfma_kernel<<<256, 512, 0, stream>>>(hcat, hidden, W1T, W2T, b1, b2, gamma, beta, out);
}

// Round 13
// 273.770 us; speedup vs baseline: 1.2451x; 1.0348x over previous
//
#include <hip/hip_runtime.h>
#include <math.h>

#define NN 50000
#define NPAD 50048      // 782 * 64
#define NTILES 3128     // NPAD / 16
#define NE 600000
#define H 128
#define ET 8
#define EPS 1e-5f
#define INVSQ 0.08838834764831845f  // 1/sqrt(128)

#define QKV_B 782       // NPAD/64 qkv blocks
#define SCAT_B 1172     // ceil(NE/512) scatter blocks

typedef __attribute__((ext_vector_type(8))) short bf16x8;
typedef __attribute__((ext_vector_type(8))) unsigned short u16x8;
typedef __attribute__((ext_vector_type(4))) float f32x4;

static __device__ inline float bf_lo(unsigned int w) { return __uint_as_float(w << 16); }
static __device__ inline float bf_hi(unsigned int w) { return __uint_as_float(w & 0xFFFF0000u); }
static __device__ inline float bfu(unsigned short v) {
  return __uint_as_float((unsigned int)v << 16);
}
static __device__ inline unsigned short f2bf(float f) {
  unsigned int u = __float_as_uint(f);
  return (unsigned short)((u + 0x7FFFu + ((u >> 16) & 1u)) >> 16);  // RNE
}

// ================= fused prep: hidden->bf16, weights->bf16^T, etype tables, degree hist =======
#define PH_B 3125
#define PW_B 384
#define ET_B 8
#define HIST_B 2344

__global__ __launch_bounds__(256) void prep_all_kernel(
    const float* __restrict__ hidden, const float* __restrict__ edge_emb,
    const float* __restrict__ Wq, const float* __restrict__ Wk, const float* __restrict__ Wv,
    const float* __restrict__ W1, const float* __restrict__ W2,
    const float* __restrict__ Web, const float* __restrict__ beb,
    const int* __restrict__ tgt,
    unsigned short* __restrict__ hcat, unsigned short* __restrict__ WqkvT,
    unsigned short* __restrict__ W1T, unsigned short* __restrict__ W2T,
    unsigned short* __restrict__ KefTT, float* __restrict__ Vef, float* __restrict__ ebuf,
    int* __restrict__ deg) {
  const int blk = blockIdx.x;
  const int t = threadIdx.x;
  if (blk < PH_B) {
    // hidden fp32 -> bf16 into hcat[:, 0:128] (row stride 256)
    int g = blk * 256 + t;  // NN*16 = 800000 exactly
    int row = g >> 4, seg = g & 15;
    const float4* src = (const float4*)(hidden + (size_t)row * 128 + seg * 8);
    float4 x0 = src[0], x1 = src[1];
    u16x8 o;
    o[0] = f2bf(x0.x); o[1] = f2bf(x0.y); o[2] = f2bf(x0.z); o[3] = f2bf(x0.w);
    o[4] = f2bf(x1.x); o[5] = f2bf(x1.y); o[6] = f2bf(x1.z); o[7] = f2bf(x1.w);
    *(u16x8*)(hcat + (size_t)row * 256 + seg * 8) = o;
  } else if (blk < PH_B + PW_B) {
    int idx = (blk - PH_B) * 256 + t;
    if (idx < 49152) {
      int r = idx >> 7, k = idx & 127;
      const float* W = (r < 128) ? Wq : (r < 256) ? Wk : Wv;
      WqkvT[idx] = f2bf(W[k * 128 + (r & 127)]);
    } else if (idx < 81920) {
      int j = idx - 49152;
      int r = j >> 8, k = j & 255;
      W1T[j] = f2bf(W1[k * 128 + r]);
    } else if (idx < 98304) {
      int j = idx - 81920;
      int r = j >> 7, k = j & 127;
      W2T[j] = f2bf(W2[k * 128 + r]);
    }
  } else if (blk < PH_B + PW_B + ET_B) {
    // per-edge-type tables: KefTT[et][k] bf16 (ee@Wk, padded to 16 rows),
    // Vef[et][k] fp32 (ee@Wv), ebuf = ee@Web + beb
    int e = blk - (PH_B + PW_B);
    if (t < 128) {
      float sk = 0.f, sv = 0.f;
      for (int i = 0; i < 128; ++i) {
        float ev = edge_emb[e * 128 + i];
        sk = fmaf(ev, Wk[i * 128 + t], sk);
        sv = fmaf(ev, Wv[i * 128 + t], sv);
      }
      KefTT[e * 128 + t] = f2bf(sk);
      KefTT[(e + 8) * 128 + t] = 0;  // pad cols 8-15
      Vef[e * 128 + t] = sv;
    } else if (t == 128) {
      float s2 = beb[0];
      for (int i = 0; i < 128; ++i) s2 = fmaf(edge_emb[e * 128 + i], Web[i], s2);
      ebuf[e] = s2;
    }
  } else {
    int e = (blk - (PH_B + PW_B + ET_B)) * 256 + t;
    if (e < NE) atomicAdd(&deg[tgt[e]], 1);
  }
}

// ---------------- QKV GEMM via MFMA + MFMA qke tail, FUSED with edge scatter ----------------
// blocks [0, QKV_B): qkv (8 waves, 2 row x 4 col groups; waves 0-3 do the qke MFMA tail)
// blocks [QKV_B, QKV_B+SCAT_B): CSR scatter (independent work, overlaps with qkv)
__global__ __launch_bounds__(512) void qkv_scatter_kernel(
    const unsigned short* __restrict__ hcat, const unsigned short* __restrict__ WqkvT,
    const float* __restrict__ bq, const float* __restrict__ bk, const float* __restrict__ bv,
    const unsigned short* __restrict__ KefTT, const float* __restrict__ ebuf,
    const int* __restrict__ srcp, const int* __restrict__ tgtp, const int* __restrict__ etyp,
    int* __restrict__ cursor, int* __restrict__ packed,
    unsigned short* __restrict__ Qb, unsigned short* __restrict__ KV_u16,
    float* __restrict__ qke) {
  __shared__ unsigned short stage[64][392];
  const int tid = threadIdx.x;
  const int blk = blockIdx.x;

  if (blk >= QKV_B) {
    // ---- scatter section ----
    int e = (blk - QKV_B) * 512 + tid;
    if (e < NE) {
      int pos = atomicAdd(&cursor[tgtp[e]], 1);
      packed[pos] = srcp[e] | (etyp[e] << 16);  // src < 65536, et < 8
    }
    return;
  }

  const int w = tid >> 6, l = tid & 63;
  const int wr = w >> 2, wc = w & 3;
  const int lr = l & 15, lg = l >> 4;

  f32x4 acc[2][6] = {};
  const unsigned short* Ab = hcat + (size_t)(blk * 64 + wr * 32 + lr) * 256 + lg * 8;
  const unsigned short* Bb = WqkvT + (size_t)(wc * 96 + lr) * 128 + lg * 8;
#pragma unroll
  for (int ks = 0; ks < 4; ++ks) {
    bf16x8 a0 = *(const bf16x8*)(Ab + ks * 32);
    bf16x8 a1 = *(const bf16x8*)(Ab + 16 * 256 + ks * 32);
#pragma unroll
    for (int ct = 0; ct < 6; ++ct) {
      bf16x8 b = *(const bf16x8*)(Bb + ct * 16 * 128 + ks * 32);
      acc[0][ct] = __builtin_amdgcn_mfma_f32_16x16x32_bf16(a0, b, acc[0][ct], 0, 0, 0);
      acc[1][ct] = __builtin_amdgcn_mfma_f32_16x16x32_bf16(a1, b, acc[1][ct], 0, 0, 0);
    }
  }
  // bias + scale + convert -> LDS stage in FINAL memory layout:
  //   row u16 layout: [0,128)   = Q col c (scaled by 1/sqrt(128))
  //                   [128,384) = KV interleave: K col j -> 128 + (j>>1)*4 + (j&1)
  //                               V col j -> 128 + (j>>1)*4 + 2 + (j&1)
#pragma unroll
  for (int ct = 0; ct < 6; ++ct) {
    int c = wc * 96 + ct * 16 + lr;
    float bias = (c < 128) ? bq[c] : (c < 256) ? bk[c - 128] : bv[c - 256];
    float sc = (c < 128) ? INVSQ : 1.f;
    int off;
    if (c < 128) off = c;
    else if (c < 256) { int j = c - 128; off = 128 + ((j >> 1) << 2) + (j & 1); }
    else { int j = c - 256; off = 128 + ((j >> 1) << 2) + 2 + (j & 1); }
#pragma unroll
    for (int mt = 0; mt < 2; ++mt)
#pragma unroll
      for (int j = 0; j < 4; ++j)
        stage[wr * 32 + mt * 16 + lg * 4 + j][off] = f2bf((acc[mt][ct][j] + bias) * sc);
  }
  __syncthreads();
  // coalesced 16B stores
  for (int idx = tid; idx < 64 * 48; idx += 512) {
    int r = idx / 48, g = idx % 48;
    int row = blk * 64 + r;
    if (row >= NN) continue;
    u16x8 v = *(const u16x8*)(&stage[r][g * 8]);
    if (g < 16) *(u16x8*)(Qb + (size_t)row * 128 + g * 8) = v;
    else *(u16x8*)(KV_u16 + (size_t)row * 256 + (g - 16) * 8) = v;
  }
  // MFMA qke tail: wave w<4 handles 16 nodes (rows w*16..w*16+15 of stage).
  if (w < 4) {
    f32x4 aq = {0.f, 0.f, 0.f, 0.f};
    const unsigned short* qrow = &stage[w * 16 + lr][0];
    const unsigned short* brow = KefTT + lr * 128;
#pragma unroll
    for (int ks = 0; ks < 4; ++ks) {
      bf16x8 af = *(const bf16x8*)(qrow + lg * 8 + ks * 32);
      bf16x8 bf = *(const bf16x8*)(brow + lg * 8 + ks * 32);
      aq = __builtin_amdgcn_mfma_f32_16x16x32_bf16(af, bf, aq, 0, 0, 0);
    }
    if (lr < 8) {
      float ebv = ebuf[lr];
#pragma unroll
      for (int j = 0; j < 4; ++j) {
        int node = blk * 64 + w * 16 + lg * 4 + j;
        if (node < NN) qke[(size_t)node * 8 + lr] = aq[j] + ebv;
      }
    }
  }
}

// ---------------- CSR build: scans ----------------
__global__ __launch_bounds__(256) void scan1_kernel(const int* __restrict__ deg,
                                                    int* __restrict__ excl,
                                                    int* __restrict__ sums) {
  __shared__ int buf[256];
  int idx = blockIdx.x * 256 + threadIdx.x;
  int v = (idx < NN) ? deg[idx] : 0;
  buf[threadIdx.x] = v;
  __syncthreads();
  for (int o = 1; o < 256; o <<= 1) {
    int tv = (threadIdx.x >= o) ? buf[threadIdx.x - o] : 0;
    __syncthreads();
    buf[threadIdx.x] += tv;
    __syncthreads();
  }
  if (idx < NN) excl[idx] = buf[threadIdx.x] - v;
  if (threadIdx.x == 255) sums[blockIdx.x] = buf[255];
}

__global__ __launch_bounds__(256) void scan2_kernel(int* __restrict__ sums, int nb) {
  __shared__ int buf[256];
  int v = (threadIdx.x < nb) ? sums[threadIdx.x] : 0;
  buf[threadIdx.x] = v;
  __syncthreads();
  for (int o = 1; o < 256; o <<= 1) {
    int tv = (threadIdx.x >= o) ? buf[threadIdx.x - o] : 0;
    __syncthreads();
    buf[threadIdx.x] += tv;
    __syncthreads();
  }
  if (threadIdx.x < nb) sums[threadIdx.x] = buf[threadIdx.x] - v;  // exclusive
}

__global__ __launch_bounds__(256) void scan3_kernel(const int* __restrict__ excl,
                                                    const int* __restrict__ sums,
                                                    int* __restrict__ row_off,
                                                    int* __restrict__ cursor) {
  int idx = blockIdx.x * 256 + threadIdx.x;
  if (idx < NN) {
    int r = excl[idx] + sums[blockIdx.x];
    row_off[idx] = r;
    cursor[idx] = r;
  }
  if (idx == 0) row_off[NN] = NE;
}

// ---------------- attention: one wave/node, 16 lanes/edge, 8 edges in flight --------------
// No-max softmax (logit range ~±8 is safe in fp32). qke folds q·Ke + eb per (node, etype).
// V-side etype fold: agg = sum pe*v + sum_et (sum_{e in et} pe) * Vef[et] — the second term
// is applied once per node in the epilogue (lane m<8 tracks etype m's exp-sum).
__global__ __launch_bounds__(256) void attn_kernel(
    const unsigned short* __restrict__ Qb, const uint4* __restrict__ KV4,
    const float* __restrict__ qke, const float* __restrict__ Vef,
    const int* __restrict__ row_off, const int* __restrict__ packed,
    unsigned short* __restrict__ hcat_u16) {
  const int wid = (blockIdx.x * blockDim.x + threadIdx.x) >> 6;
  const int lane = threadIdx.x & 63;
  const int g = lane >> 4, m = lane & 15;
  const int beg = row_off[wid], end = row_off[wid + 1];
  // q: 8 cols starting 8m (bf16, pre-scaled by 1/sqrt(128))
  u16x8 qv = *(const u16x8*)(Qb + (size_t)wid * 128 + m * 8);
  float q[8];
#pragma unroll
  for (int j = 0; j < 8; ++j) q[j] = bfu(qv[j]);
  const float* qkb = qke + (size_t)wid * 8;
  const bool mlt8 = (m < 8);
  float a[8] = {0.f, 0.f, 0.f, 0.f, 0.f, 0.f, 0.f, 0.f};
  float s = 0.f, se = 0.f;
  for (int i = beg; i < end; i += 8) {
    int iA = i + g, iB = i + 4 + g;
    bool vA = iA < end, vB = iB < end;
    int pA = packed[vA ? iA : beg];
    int pB = packed[vB ? iB : beg];
    int sA = pA & 0xFFFF, eA = pA >> 16;
    int sB = pB & 0xFFFF, eB = pB >> 16;
    // KV row = 32 uint4; lane m reads uint4 2m, 2m+1 (cols 8m..8m+7)
    const uint4* rowA = KV4 + (size_t)sA * 32 + m * 2;
    const uint4* rowB = KV4 + (size_t)sB * 32 + m * 2;
    uint4 xA0 = rowA[0], xA1 = rowA[1];
    uint4 xB0 = rowB[0], xB1 = rowB[1];
    // x: {kpair, vpair, kpair, vpair}
    float dA, dB;
    dA = bf_lo(xA0.x) * q[0];
    dB = bf_lo(xB0.x) * q[0];
    dA = fmaf(bf_hi(xA0.x), q[1], dA);
    dB = fmaf(bf_hi(xB0.x), q[1], dB);
    dA = fmaf(bf_lo(xA0.z), q[2], dA);
    dB = fmaf(bf_lo(xB0.z), q[2], dB);
    dA = fmaf(bf_hi(xA0.z), q[3], dA);
    dB = fmaf(bf_hi(xB0.z), q[3], dB);
    dA = fmaf(bf_lo(xA1.x), q[4], dA);
    dB = fmaf(bf_lo(xB1.x), q[4], dB);
    dA = fmaf(bf_hi(xA1.x), q[5], dA);
    dB = fmaf(bf_hi(xB1.x), q[5], dB);
    dA = fmaf(bf_lo(xA1.z), q[6], dA);
    dB = fmaf(bf_lo(xB1.z), q[6], dB);
    dA = fmaf(bf_hi(xA1.z), q[7], dA);
    dB = fmaf(bf_hi(xB1.z), q[7], dB);
#pragma unroll
    for (int o = 8; o >= 1; o >>= 1) {
      dA += __shfl_xor(dA, o);
      dB += __shfl_xor(dB, o);
    }
    float peA = __expf(dA + qkb[eA]);
    float peB = __expf(dB + qkb[eB]);
    peA = vA ? peA : 0.f;
    peB = vB ? peB : 0.f;
    s += peA + peB;
    se += (mlt8 && eA == m) ? peA : 0.f;
    se += (mlt8 && eB == m) ? peB : 0.f;
    a[0] = fmaf(peA, bf_lo(xA0.y), a[0]);
    a[1] = fmaf(peA, bf_hi(xA0.y), a[1]);
    a[2] = fmaf(peA, bf_lo(xA0.w), a[2]);
    a[3] = fmaf(peA, bf_hi(xA0.w), a[3]);
    a[4] = fmaf(peA, bf_lo(xA1.y), a[4]);
    a[5] = fmaf(peA, bf_hi(xA1.y), a[5]);
    a[6] = fmaf(peA, bf_lo(xA1.w), a[6]);
    a[7] = fmaf(peA, bf_hi(xA1.w), a[7]);
    a[0] = fmaf(peB, bf_lo(xB0.y), a[0]);
    a[1] = fmaf(peB, bf_hi(xB0.y), a[1]);
    a[2] = fmaf(peB, bf_lo(xB0.w), a[2]);
    a[3] = fmaf(peB, bf_hi(xB0.w), a[3]);
    a[4] = fmaf(peB, bf_lo(xB1.y), a[4]);
    a[5] = fmaf(peB, bf_hi(xB1.y), a[5]);
    a[6] = fmaf(peB, bf_lo(xB1.w), a[6]);
    a[7] = fmaf(peB, bf_hi(xB1.w), a[7]);
  }
  // cross-group reduce (xor 16, 32)
#pragma unroll
  for (int o = 16; o <= 32; o <<= 1) {
    s += __shfl_xor(s, o);
    se += __shfl_xor(se, o);
#pragma unroll
    for (int j = 0; j < 8; ++j) a[j] += __shfl_xor(a[j], o);
  }
  // fold per-etype V contributions (all lanes execute; only g==0 stores)
#pragma unroll
  for (int t = 0; t < 8; ++t) {
    float st = __shfl(se, (lane & 48) | t);
    const float4* vf = (const float4*)(Vef + t * 128 + m * 8);
    float4 v0 = vf[0], v1 = vf[1];
    a[0] = fmaf(st, v0.x, a[0]);
    a[1] = fmaf(st, v0.y, a[1]);
    a[2] = fmaf(st, v0.z, a[2]);
    a[3] = fmaf(st, v0.w, a[3]);
    a[4] = fmaf(st, v1.x, a[4]);
    a[5] = fmaf(st, v1.y, a[5]);
    a[6] = fmaf(st, v1.z, a[6]);
    a[7] = fmaf(st, v1.w, a[7]);
  }
  if (g == 0) {
    float inv = (s > 0.f) ? 1.f / s : 0.f;
    u16x8 o;
#pragma unroll
    for (int j = 0; j < 8; ++j) o[j] = f2bf(a[j] * inv);
    *(u16x8*)(hcat_u16 + (size_t)wid * 256 + 128 + m * 8) = o;
  }
}

// ---------------- FFN + residual + LayerNorm (MFMA, weights in LDS, persistent waves) -------
// 256 blocks x 512 threads (8 waves = 2/SIMD, up to 256 VGPR -> no spills). W1T (64KB) +
// W2T (32KB) staged once into LDS with XOR swizzle; per-wave mid buffers. LDS 130KB.
__global__ __launch_bounds__(512) void ffn_mfma_kernel(
    const unsigned short* __restrict__ hcat, const float* __restrict__ hidden,
    const unsigned short* __restrict__ W1T, const unsigned short* __restrict__ W2T,
    const float* __restrict__ b1, const float* __restrict__ b2,
    const float* __restrict__ gamma, const float* __restrict__ beta,
    float* __restrict__ out) {
  __shared__ unsigned short w1s[32768];      // 64KB swizzled [128][256]
  __shared__ unsigned short w2s[16384];      // 32KB swizzled [128][128]
  __shared__ unsigned short mids[8][2176];   // per-wave 16 x 136
  const int tid = threadIdx.x;
  const int w = tid >> 6, l = tid & 63;
  const int lr = l & 15, lg = l >> 4;

  // ---- stage weights (once per block) ----
#pragma unroll
  for (int it = 0; it < 8; ++it) {
    int idx = it * 512 + tid;                // 4096 segs of 8 u16
    int c = idx >> 5, ks8 = idx & 31;
    u16x8 v = *(const u16x8*)(W1T + c * 256 + ks8 * 8);
    int byte = (c * 512 + ks8 * 16) ^ ((c & 7) << 4);
    *(u16x8*)((char*)w1s + byte) = v;
  }
#pragma unroll
  for (int it = 0; it < 4; ++it) {
    int idx = it * 512 + tid;                // 2048 segs
    int c = idx >> 4, ks8 = idx & 15;
    u16x8 v = *(const u16x8*)(W2T + c * 128 + ks8 * 8);
    int byte = (c * 256 + ks8 * 16) ^ ((c & 7) << 4);
    *(u16x8*)((char*)w2s + byte) = v;
  }
  __syncthreads();

  // ---- per-lane constants ----
  float bias1[8], bias2[8], ga[8], be[8];
#pragma unroll
  for (int ct = 0; ct < 8; ++ct) {
    int c = ct * 16 + lr;
    bias1[ct] = b1[c];
    bias2[ct] = b2[c];
    ga[ct] = gamma[c];
    be[ct] = beta[c];
  }
  unsigned short* midw = mids[w];
  const char* w1b = (const char*)w1s;
  const char* w2b = (const char*)w2s;

  for (int t = blockIdx.x * 8 + w; t < NTILES; t += 2048) {
    // A fragments (K=256): 8 x 16B from hcat
    const unsigned short* Ab = hcat + (size_t)(t * 16 + lr) * 256 + lg * 8;
    bf16x8 a[8];
#pragma unroll
    for (int ks = 0; ks < 8; ++ks) a[ks] = *(const bf16x8*)(Ab + ks * 32);

    // GEMM1: K=256 -> 128, B from LDS
    f32x4 acc[8] = {};
#pragma unroll
    for (int ks = 0; ks < 8; ++ks) {
#pragma unroll
      for (int ct = 0; ct < 8; ++ct) {
        int byte = ((ct * 16 + lr) * 512 + (lg * 8 + ks * 32) * 2) ^ ((lr & 7) << 4);
        bf16x8 b = *(const bf16x8*)(w1b + byte);
        acc[ct] = __builtin_amdgcn_mfma_f32_16x16x32_bf16(a[ks], b, acc[ct], 0, 0, 0);
      }
    }

    // residual prefetch (consumed in epilogue; latency hidden under GEMM2)
    float res[8][4];
#pragma unroll
    for (int ct = 0; ct < 8; ++ct)
#pragma unroll
      for (int j = 0; j < 4; ++j) {
        int r = t * 16 + lg * 4 + j;
        res[ct][j] = (r < NN) ? hidden[(size_t)r * 128 + ct * 16 + lr] : 0.f;
      }

    // silu -> per-wave mid buffer
#pragma unroll
    for (int ct = 0; ct < 8; ++ct) {
      float bb = bias1[ct];
#pragma unroll
      for (int j = 0; j < 4; ++j) {
        float x = acc[ct][j] + bb;
        float sl = x / (1.f + __expf(-x));
        midw[(lg * 4 + j) * 136 + ct * 16 + lr] = f2bf(sl);
      }
    }
    asm volatile("s_waitcnt lgkmcnt(0)" ::: "memory");
    __builtin_amdgcn_sched_barrier(0);

    // GEMM2: K=128 -> 128, A from mid, B from LDS
    f32x4 acc2[8] = {};
#pragma unroll
    for (int ks = 0; ks < 4; ++ks) {
      bf16x8 a2 = *(const bf16x8*)(midw + lr * 136 + lg * 8 + ks * 32);
#pragma unroll
      for (int ct = 0; ct < 8; ++ct) {
        int byte = ((ct * 16 + lr) * 256 + (lg * 8 + ks * 32) * 2) ^ ((lr & 7) << 4);
        bf16x8 b = *(const bf16x8*)(w2b + byte);
        acc2[ct] = __builtin_amdgcn_mfma_f32_16x16x32_bf16(a2, b, acc2[ct], 0, 0, 0);
      }
    }

    // epilogue: + b2 + residual, LayerNorm, store
    float x[8][4];
#pragma unroll
    for (int ct = 0; ct < 8; ++ct)
#pragma unroll
      for (int j = 0; j < 4; ++j) x[ct][j] = acc2[ct][j] + bias2[ct] + res[ct][j];
#pragma unroll
    for (int j = 0; j < 4; ++j) {
      float s = 0.f, ss = 0.f;
#pragma unroll
      for (int ct = 0; ct < 8; ++ct) {
        s += x[ct][j];
        ss += x[ct][j] * x[ct][j];
      }
#pragma unroll
      for (int o = 8; o >= 1; o >>= 1) {
        s += __shfl_xor(s, o);
        ss += __shfl_xor(ss, o);
      }
      float mu = s * (1.f / 128.f);
      float inv = rsqrtf(ss * (1.f / 128.f) - mu * mu + EPS);
      int r = t * 16 + lg * 4 + j;
      if (r < NN) {
#pragma unroll
        for (int ct = 0; ct < 8; ++ct) {
          int c = ct * 16 + lr;
          out[(size_t)r * 128 + c] = (x[ct][j] - mu) * inv * ga[ct] + be[ct];
        }
      }
    }
  }
}

extern "C" void kernel_launch(void* const* d_in, const int* in_sizes, int n_in,
                              void* d_out, int out_size, void* d_ws, size_t ws_size,
                              hipStream_t stream) {
  const float* hidden = (const float*)d_in[0];
  const int* edge_index = (const int*)d_in[1];
  const int* edge_type = (const int*)d_in[2];
  const float* edge_emb = (const float*)d_in[3];
  const float* Wq = (const float*)d_in[4];
  const float* bq = (const float*)d_in[5];
  const float* Wk = (const float*)d_in[6];
  const float* bk = (const float*)d_in[7];
  const float* Wv = (const float*)d_in[8];
  const float* bv = (const float*)d_in[9];
  const float* Web = (const float*)d_in[10];
  const float* beb = (const float*)d_in[11];
  const float* W1 = (const float*)d_in[12];
  const float* b1 = (const float*)d_in[13];
  const float* W2 = (const float*)d_in[14];
  const float* b2 = (const float*)d_in[15];
  const float* gamma = (const float*)d_in[16];
  const float* beta = (const float*)d_in[17];
  float* out = (float*)d_out;

  const int* srcp = edge_index;
  const int* tgtp = edge_index + NE;

  size_t off = 0;
  auto alloc = [&](size_t bytes) {
    void* p = (char*)d_ws + off;
    off += (bytes + 255) & ~(size_t)255;
    return p;
  };
  unsigned short* hcat = (unsigned short*)alloc((size_t)NPAD * 256 * 2);  // [h|agg] bf16
  unsigned short* Qb = (unsigned short*)alloc((size_t)NPAD * 128 * 2);    // pre-scaled
  unsigned short* KV = (unsigned short*)alloc((size_t)NPAD * 256 * 2);    // interleaved k/v pairs
  unsigned short* WqkvT = (unsigned short*)alloc(384 * 128 * 2);
  unsigned short* W1T = (unsigned short*)alloc(128 * 256 * 2);
  unsigned short* W2T = (unsigned short*)alloc(128 * 128 * 2);
  unsigned short* KefTT = (unsigned short*)alloc(16 * 128 * 2);  // bf16 Kef^T (padded to 16)
  float* Vef = (float*)alloc(ET * H * 4);
  float* ebuf = (float*)alloc(ET * 4);
  float* qke = (float*)alloc((size_t)NN * 8 * 4);
  int* deg = (int*)alloc((size_t)NN * 4);
  int* excl = (int*)alloc((size_t)NN * 4);
  int* sums = (int*)alloc(256 * 4);
  int* row_off = (int*)alloc((size_t)(NN + 1) * 4);
  int* cursor = (int*)alloc((size_t)NN * 4);
  int* packed = (int*)alloc((size_t)NE * 4);

  hipMemsetAsync(deg, 0, (size_t)NN * 4, stream);

  const int scan_blocks = (NN + 255) / 256;  // 196

  prep_all_kernel<<<PH_B + PW_B + ET_B + HIST_B, 256, 0, stream>>>(
      hidden, edge_emb, Wq, Wk, Wv, W1, W2, Web, beb, tgtp, hcat, WqkvT, W1T, W2T, KefTT, Vef,
      ebuf, deg);
  scan1_kernel<<<scan_blocks, 256, 0, stream>>>(deg, excl, sums);
  scan2_kernel<<<1, 256, 0, stream>>>(sums, scan_blocks);
  scan3_kernel<<<scan_blocks, 256, 0, stream>>>(excl, sums, row_off, cursor);
  qkv_scatter_kernel<<<QKV_B + SCAT_B, 512, 0, stream>>>(
      hcat, WqkvT, bq, bk, bv, KefTT, ebuf, srcp, tgtp, edge_type, cursor, packed, Qb, KV, qke);
  attn_kernel<<<(NN * 64) / 256, 256, 0, stream>>>(Qb, (const uint4*)KV, qke, Vef, row_off,
                                                   packed, hcat);
  ffn_mfma_kernel<<<256, 512, 0, stream>>>(hcat, hidden, W1T, W2T, b1, b2, gamma, beta, out);
}